// Round 1
// baseline (889.941 us; speedup 1.0000x reference)
//
#include <hip/hip_runtime.h>
#include <stdint.h>

#define TT 2048
#define CC 1024

typedef short bf16x8 __attribute__((ext_vector_type(8)));
typedef float f32x4 __attribute__((ext_vector_type(4)));
typedef __attribute__((address_space(3))) uint32_t lds_u32_t;
typedef const __attribute__((address_space(1))) uint32_t glb_u32_t;

__device__ inline unsigned short f2b(float f) {
  union { float f; unsigned u; } c; c.f = f;
  unsigned u = c.u;
  return (unsigned short)((u + 0x7fffu + ((u >> 16) & 1u)) >> 16);
}
__device__ inline float b2f(unsigned short s) {
  union { unsigned u; float f; } c; c.u = ((unsigned)s) << 16; return c.f;
}

__device__ inline void gl_lds16(const void* g, void* l) {
  glb_u32_t* gp = (glb_u32_t*)(uintptr_t)g;
  lds_u32_t* lp = (lds_u32_t*)(uint32_t)(uintptr_t)l;
  __builtin_amdgcn_global_load_lds(gp, lp, 16, 0, 0);
}

// ---------------- transpose + f32->bf16 convert: out[C,R] = in[R,C] ----------------
__global__ void transpose_cvt(const float* __restrict__ in, unsigned short* __restrict__ out,
                              int R, int C) {
  __shared__ float tile[32][33];
  int c0 = blockIdx.x * 32, r0 = blockIdx.y * 32;
  int tx = threadIdx.x, ty = threadIdx.y;  // 32x8
  for (int i = ty; i < 32; i += 8) {
    int r = r0 + i, c = c0 + tx;
    tile[i][tx] = (r < R && c < C) ? in[(size_t)r * C + c] : 0.f;
  }
  __syncthreads();
  int rr = r0 + tx;
  for (int i = ty; i < 32; i += 8) {
    int cc = c0 + i;
    if (cc < C && rr < R) out[(size_t)cc * R + rr] = f2b(tile[tx][i]);
  }
}

// ---------------- token shift: xx = shift(x)-x ; xxx = bf16(x + xx*tmx) ----------------
__global__ void shift_mix(const float* __restrict__ x, const float* __restrict__ tmx,
                          float* __restrict__ xx, unsigned short* __restrict__ xxx) {
  int idx = blockIdx.x * 256 + threadIdx.x;  // float4 groups, 2M total
  int c4 = idx & 255;
  int row = idx >> 8;
  int t = row & (TT - 1);
  const float4* x4 = (const float4*)x;
  float4 xv = x4[idx];
  float4 pv = make_float4(0.f, 0.f, 0.f, 0.f);
  if (t > 0) pv = x4[idx - 256];
  float4 d;
  d.x = pv.x - xv.x; d.y = pv.y - xv.y; d.z = pv.z - xv.z; d.w = pv.w - xv.w;
  ((float4*)xx)[idx] = d;
  float4 tm = ((const float4*)tmx)[c4];
  ushort4 o;
  o.x = f2b(xv.x + d.x * tm.x);
  o.y = f2b(xv.y + d.y * tm.y);
  o.z = f2b(xv.z + d.z * tm.z);
  o.w = f2b(xv.w + d.w * tm.w);
  ((ushort4*)xxx)[idx] = o;
}

// ---------------- bf16 MFMA GEMM, 128x128 tile, BK=32, global_load_lds staging -------
// A: [M,K] bf16 row-major (lda). Bt: [N,K] bf16 row-major (ldb) == B transposed.
// modes: 0 f32 store [row*ldc+col]; 1 tanh->bf16 [row*ldc+col];
//        2 gate: outB = bf16(x + xx*(tm[col]+acc)); 3 perm bf16 [B,H,T,16];
//        4 decay: outF[perm] = exp(-exp(tm[col]+acc))
__global__ __launch_bounds__(256) void gemm_bf16(
    const unsigned short* __restrict__ A, const unsigned short* __restrict__ Bt,
    int N, int K, int lda, int ldb, int mode, int ldc,
    float* __restrict__ outF, unsigned short* __restrict__ outB,
    const float* __restrict__ xg, const float* __restrict__ xxg,
    const float* __restrict__ tm) {
  __shared__ __align__(16) unsigned short As[4096];  // [kb(4)][m(128)][8]
  __shared__ __align__(16) unsigned short Bs[4096];
  int tid = threadIdx.x;
  int w = tid >> 6, lane = tid & 63;
  int quad = lane >> 4, l16 = lane & 15;
  int rowBase = blockIdx.y * 128;
  int colBase = blockIdx.x * 128;
  int waveM = (w >> 1) * 64, waveN = (w & 1) * 64;

  f32x4 acc[4][4];
#pragma unroll
  for (int i = 0; i < 4; i++)
#pragma unroll
    for (int j = 0; j < 4; j++) acc[i][j] = (f32x4){0.f, 0.f, 0.f, 0.f};

  for (int k0 = 0; k0 < K; k0 += 32) {
    __syncthreads();
#pragma unroll
    for (int i = 0; i < 2; i++) {
      int c = w * 2 + i;          // 0..7
      int kb = c >> 1;            // == w
      int mh = (c & 1) * 64;
      const unsigned short* ga = A + (size_t)(rowBase + mh + lane) * lda + k0 + kb * 8;
      gl_lds16(ga, (char*)As + (size_t)(kb * 128 + mh) * 16);
      const unsigned short* gb = Bt + (size_t)(colBase + mh + lane) * ldb + k0 + kb * 8;
      gl_lds16(gb, (char*)Bs + (size_t)(kb * 128 + mh) * 16);
    }
    __syncthreads();
    bf16x8 af[4], bfr[4];
#pragma unroll
    for (int mt = 0; mt < 4; mt++)
      af[mt] = *(const bf16x8*)(As + (size_t)(quad * 128 + waveM + mt * 16 + l16) * 8);
#pragma unroll
    for (int nt = 0; nt < 4; nt++)
      bfr[nt] = *(const bf16x8*)(Bs + (size_t)(quad * 128 + waveN + nt * 16 + l16) * 8);
#pragma unroll
    for (int mt = 0; mt < 4; mt++)
#pragma unroll
      for (int nt = 0; nt < 4; nt++)
        acc[mt][nt] = __builtin_amdgcn_mfma_f32_16x16x32_bf16(af[mt], bfr[nt], acc[mt][nt], 0, 0, 0);
  }

#pragma unroll
  for (int mt = 0; mt < 4; mt++) {
#pragma unroll
    for (int nt = 0; nt < 4; nt++) {
#pragma unroll
      for (int rg = 0; rg < 4; rg++) {
        int row = rowBase + waveM + mt * 16 + quad * 4 + rg;
        int col = colBase + waveN + nt * 16 + l16;
        if (col >= N) continue;
        float val = acc[mt][nt][rg];
        if (mode == 0) {
          outF[(size_t)row * ldc + col] = val;
        } else if (mode == 1) {
          outB[(size_t)row * ldc + col] = f2b(tanhf(val));
        } else if (mode == 2) {
          size_t o = (size_t)row * CC + col;
          outB[o] = f2b(xg[o] + xxg[o] * (tm[col] + val));
        } else if (mode == 3) {
          int b = row >> 11, t = row & (TT - 1), h = col >> 4, n = col & 15;
          outB[(size_t)((b * 64 + h) * TT + t) * 16 + n] = f2b(val);
        } else {
          int b = row >> 11, t = row & (TT - 1), h = col >> 4, n = col & 15;
          outF[(size_t)((b * 64 + h) * TT + t) * 16 + n] = expf(-expf(tm[col] + val));
        }
      }
    }
  }
}

// ---------------- WKV6 sequential scan: one wave per (b,h) ----------------
// r,k,v: bf16 [B*H, T, 16]; wd: f32 [B*H, T, 16]; u: f32 [64,16]; y: f32 [B,T,C]
__global__ __launch_bounds__(64) void wkv_scan(
    const unsigned short* __restrict__ r, const unsigned short* __restrict__ k,
    const unsigned short* __restrict__ v, const float* __restrict__ wd,
    const float* __restrict__ u, float* __restrict__ y) {
  __shared__ __align__(16) float lr[256], lk[256], lv[256], lw[256];
  int bh = blockIdx.x;
  int b = bh >> 6, h = bh & 63;
  int lane = threadIdx.x;
  int j = lane & 15, p = lane >> 4;  // lane owns S[p*4..p*4+3][j]
  float u4[4];
  float S0 = 0.f, S1 = 0.f, S2 = 0.f, S3 = 0.f;
#pragma unroll
  for (int q = 0; q < 4; q++) u4[q] = u[h * 16 + p * 4 + q];
  size_t base = (size_t)bh * TT * 16;

  for (int t0 = 0; t0 < TT; t0 += 16) {
    __syncthreads();
    {
      size_t off = base + (size_t)t0 * 16;
      ushort4 rv = ((const ushort4*)(r + off))[lane];
      ushort4 kv4 = ((const ushort4*)(k + off))[lane];
      ushort4 vv = ((const ushort4*)(v + off))[lane];
      float4 wv = ((const float4*)(wd + off))[lane];
      ((float4*)lr)[lane] = make_float4(b2f(rv.x), b2f(rv.y), b2f(rv.z), b2f(rv.w));
      ((float4*)lk)[lane] = make_float4(b2f(kv4.x), b2f(kv4.y), b2f(kv4.z), b2f(kv4.w));
      ((float4*)lv)[lane] = make_float4(b2f(vv.x), b2f(vv.y), b2f(vv.z), b2f(vv.w));
      ((float4*)lw)[lane] = wv;
    }
    __syncthreads();
#pragma unroll
    for (int s = 0; s < 16; s++) {
      float4 rr = *(const float4*)(lr + s * 16 + p * 4);
      float4 kk = *(const float4*)(lk + s * 16 + p * 4);
      float4 ww = *(const float4*)(lw + s * 16 + p * 4);
      float vj = lv[s * 16 + j];
      float kv, part;
      kv = kk.x * vj; part = rr.x * fmaf(u4[0], kv, S0); S0 = fmaf(ww.x, S0, kv);
      kv = kk.y * vj; part = fmaf(rr.y, fmaf(u4[1], kv, S1), part); S1 = fmaf(ww.y, S1, kv);
      kv = kk.z * vj; part = fmaf(rr.z, fmaf(u4[2], kv, S2), part); S2 = fmaf(ww.z, S2, kv);
      kv = kk.w * vj; part = fmaf(rr.w, fmaf(u4[3], kv, S3), part); S3 = fmaf(ww.w, S3, kv);
      part += __shfl_xor(part, 16, 64);
      part += __shfl_xor(part, 32, 64);
      if (p == 0) y[(size_t)(b * TT + t0 + s) * CC + h * 16 + j] = part;
    }
  }
}

// ---------------- LayerNorm -> bf16 ----------------
__global__ __launch_bounds__(256) void ln_fused(const float* __restrict__ y,
                                                const float* __restrict__ g,
                                                const float* __restrict__ be,
                                                unsigned short* __restrict__ out) {
  int row = blockIdx.x;
  int tid = threadIdx.x;
  float4 val = ((const float4*)(y + (size_t)row * CC))[tid];
  float s = val.x + val.y + val.z + val.w;
  float sq = val.x * val.x + val.y * val.y + val.z * val.z + val.w * val.w;
#pragma unroll
  for (int m = 1; m < 64; m <<= 1) {
    s += __shfl_xor(s, m, 64);
    sq += __shfl_xor(sq, m, 64);
  }
  __shared__ float ss[4], s2[4];
  int w = tid >> 6;
  if ((tid & 63) == 0) { ss[w] = s; s2[w] = sq; }
  __syncthreads();
  s = ss[0] + ss[1] + ss[2] + ss[3];
  sq = s2[0] + s2[1] + s2[2] + s2[3];
  float mu = s * (1.f / 1024.f);
  float var = sq * (1.f / 1024.f) - mu * mu;
  float rstd = rsqrtf(var + 1e-5f);
  float4 gg = ((const float4*)g)[tid];
  float4 bb = ((const float4*)be)[tid];
  ushort4 o;
  o.x = f2b((val.x - mu) * rstd * gg.x + bb.x);
  o.y = f2b((val.y - mu) * rstd * gg.y + bb.y);
  o.z = f2b((val.z - mu) * rstd * gg.z + bb.z);
  o.w = f2b((val.w - mu) * rstd * gg.w + bb.w);
  ((ushort4*)(out + (size_t)row * CC))[tid] = o;
}

extern "C" void kernel_launch(void* const* d_in, const int* in_sizes, int n_in,
                              void* d_out, int out_size, void* d_ws, size_t ws_size,
                              hipStream_t stream) {
  (void)in_sizes; (void)n_in; (void)out_size; (void)ws_size;
  const float* x = (const float*)d_in[0];
  const float* tmx = (const float*)d_in[1];
  const float* tmw = (const float*)d_in[2];
  const float* tmk = (const float*)d_in[3];
  const float* tmv = (const float*)d_in[4];
  const float* tmr = (const float*)d_in[5];
  const float* w1 = (const float*)d_in[6];
  const float* w2 = (const float*)d_in[7];
  const float* tdecay = (const float*)d_in[8];
  const float* dw1 = (const float*)d_in[9];
  const float* dw2 = (const float*)d_in[10];
  const float* faaaa = (const float*)d_in[11];
  const float* Wr = (const float*)d_in[12];
  const float* Wk = (const float*)d_in[13];
  const float* Wv = (const float*)d_in[14];
  const float* Wo = (const float*)d_in[15];
  const float* lng = (const float*)d_in[16];
  const float* lnb = (const float*)d_in[17];
  float* out = (float*)d_out;

  char* ws = (char*)d_ws;
  const size_t MBy = 1ull << 20;
  unsigned short* rb = (unsigned short*)(ws + 0);          // 16MB  bf16 [BH,T,16]
  unsigned short* kbuf = (unsigned short*)(ws + 16 * MBy); // 16MB
  unsigned short* vbuf = (unsigned short*)(ws + 32 * MBy); // 16MB
  float* wdb = (float*)(ws + 48 * MBy);                    // 32MB  f32 [BH,T,16]
  float* xxb = (float*)(ws + 80 * MBy);                    // 32MB (dead after gates)
  float* yb = (float*)(ws + 80 * MBy);                     // 32MB (reuse)
  unsigned short* xxxb = (unsigned short*)(ws + 112 * MBy);// 16MB (dead after mix)
  unsigned short* xwb = (unsigned short*)(ws + 112 * MBy); // reuse? no: xxx dead after mix; see below
  unsigned short* xrb = (unsigned short*)(ws + 128 * MBy);
  unsigned short* xkb = (unsigned short*)(ws + 144 * MBy);
  unsigned short* xvb = (unsigned short*)(ws + 160 * MBy);
  unsigned short* ynb = (unsigned short*)(ws + 144 * MBy); // reuse xk after k-GEMM
  unsigned short* mtmpb = (unsigned short*)(ws + 176 * MBy); // 2MB bf16 [8192,128]
  unsigned short* dtmpb = (unsigned short*)(ws + 178 * MBy); // 1MB bf16 [8192,64]
  char* wreg = ws + 180 * MBy;
  unsigned short* w1t = (unsigned short*)(wreg);               // [128,1024]
  unsigned short* w2t = (unsigned short*)(wreg + 256 * 1024);  // 4x[1024,32]
  unsigned short* dw1t = (unsigned short*)(wreg + 512 * 1024); // [64,1024]
  unsigned short* dw2t = (unsigned short*)(wreg + 640 * 1024); // [1024,64]
  unsigned short* Wrt = (unsigned short*)(wreg + 768 * 1024);  // [1024,1024]
  unsigned short* Wkt = Wrt + 1024 * 1024;
  unsigned short* Wvt = Wkt + 1024 * 1024;
  unsigned short* Wot = Wvt + 1024 * 1024;

  dim3 tb(32, 8);
  transpose_cvt<<<dim3(4, 32), tb, 0, stream>>>(w1, w1t, 1024, 128);
  for (int g = 0; g < 4; g++)
    transpose_cvt<<<dim3(32, 1), tb, 0, stream>>>(w2 + (size_t)g * 32 * 1024,
                                                  w2t + (size_t)g * 1024 * 32, 32, 1024);
  transpose_cvt<<<dim3(2, 32), tb, 0, stream>>>(dw1, dw1t, 1024, 64);
  transpose_cvt<<<dim3(32, 2), tb, 0, stream>>>(dw2, dw2t, 64, 1024);
  transpose_cvt<<<dim3(32, 32), tb, 0, stream>>>(Wr, Wrt, 1024, 1024);
  transpose_cvt<<<dim3(32, 32), tb, 0, stream>>>(Wk, Wkt, 1024, 1024);
  transpose_cvt<<<dim3(32, 32), tb, 0, stream>>>(Wv, Wvt, 1024, 1024);
  transpose_cvt<<<dim3(32, 32), tb, 0, stream>>>(Wo, Wot, 1024, 1024);

  shift_mix<<<8192, 256, 0, stream>>>(x, tmx, xxb, xxxb);

  // mixer: mtmp = tanh(xxx @ w1)  [8192,128]
  gemm_bf16<<<dim3(1, 64), 256, 0, stream>>>(xxxb, w1t, 128, 1024, 1024, 1024, 1, 128,
                                             nullptr, mtmpb, nullptr, nullptr, nullptr);
  // gates: xg = bf16(x + xx*(tm_g + mtmp[:,g] @ w2[g]))
  {
    const float* tms[4] = {tmw, tmk, tmv, tmr};
    unsigned short* xouts[4] = {xwb, xkb, xvb, xrb};
    for (int g = 0; g < 4; g++)
      gemm_bf16<<<dim3(8, 64), 256, 0, stream>>>(mtmpb + g * 32, w2t + (size_t)g * 1024 * 32,
                                                 1024, 32, 128, 32, 2, 1024,
                                                 nullptr, xouts[g], x, xxb, tms[g]);
  }
  // decay: dtmp = tanh(xw @ dw1); wd = exp(-exp(tdecay + dtmp @ dw2)) (permuted)
  gemm_bf16<<<dim3(1, 64), 256, 0, stream>>>(xwb, dw1t, 64, 1024, 1024, 1024, 1, 64,
                                             nullptr, dtmpb, nullptr, nullptr, nullptr);
  gemm_bf16<<<dim3(8, 64), 256, 0, stream>>>(dtmpb, dw2t, 1024, 64, 64, 64, 4, 1024,
                                             wdb, nullptr, nullptr, nullptr, tdecay);
  // projections (permuted bf16 [BH,T,16])
  gemm_bf16<<<dim3(8, 64), 256, 0, stream>>>(xrb, Wrt, 1024, 1024, 1024, 1024, 3, 1024,
                                             nullptr, rb, nullptr, nullptr, nullptr);
  gemm_bf16<<<dim3(8, 64), 256, 0, stream>>>(xkb, Wkt, 1024, 1024, 1024, 1024, 3, 1024,
                                             nullptr, kbuf, nullptr, nullptr, nullptr);
  gemm_bf16<<<dim3(8, 64), 256, 0, stream>>>(xvb, Wvt, 1024, 1024, 1024, 1024, 3, 1024,
                                             nullptr, vbuf, nullptr, nullptr, nullptr);

  wkv_scan<<<256, 64, 0, stream>>>(rb, kbuf, vbuf, wdb, faaaa, yb);
  ln_fused<<<8192, 256, 0, stream>>>(yb, lng, lnb, ynb);
  // out = ynorm @ W_o
  gemm_bf16<<<dim3(8, 64), 256, 0, stream>>>(ynb, Wot, 1024, 1024, 1024, 1024, 0, 1024,
                                             out, nullptr, nullptr, nullptr, nullptr);
}

// Round 2
// 651.272 us; speedup vs baseline: 1.3665x; 1.3665x over previous
//
#include <hip/hip_runtime.h>
#include <stdint.h>

#define TT 2048
#define CC 1024

typedef short bf16x8 __attribute__((ext_vector_type(8)));
typedef float f32x4 __attribute__((ext_vector_type(4)));
typedef __attribute__((address_space(3))) uint32_t lds_u32_t;
typedef const __attribute__((address_space(1))) uint32_t glb_u32_t;

__device__ inline unsigned short f2b(float f) {
  union { float f; unsigned u; } c; c.f = f;
  unsigned u = c.u;
  return (unsigned short)((u + 0x7fffu + ((u >> 16) & 1u)) >> 16);
}
__device__ inline float b2f(unsigned short s) {
  union { unsigned u; float f; } c; c.u = ((unsigned)s) << 16; return c.f;
}

__device__ inline void gl_lds16(const void* g, void* l) {
  glb_u32_t* gp = (glb_u32_t*)(uintptr_t)g;
  lds_u32_t* lp = (lds_u32_t*)(uint32_t)(uintptr_t)l;
  __builtin_amdgcn_global_load_lds(gp, lp, 16, 0, 0);
}

// ---------------- transpose + f32->bf16 convert: out[C,R] = in[R,C] ----------------
__global__ void transpose_cvt(const float* __restrict__ in, unsigned short* __restrict__ out,
                              int R, int C) {
  __shared__ float tile[32][33];
  int c0 = blockIdx.x * 32, r0 = blockIdx.y * 32;
  int tx = threadIdx.x, ty = threadIdx.y;  // 32x8
  for (int i = ty; i < 32; i += 8) {
    int r = r0 + i, c = c0 + tx;
    tile[i][tx] = (r < R && c < C) ? in[(size_t)r * C + c] : 0.f;
  }
  __syncthreads();
  int rr = r0 + tx;
  for (int i = ty; i < 32; i += 8) {
    int cc = c0 + i;
    if (cc < C && rr < R) out[(size_t)cc * R + rr] = f2b(tile[tx][i]);
  }
}

// ---------------- token shift: xx = shift(x)-x ; xxx = bf16(x + xx*tmx) ----------------
__global__ void shift_mix(const float* __restrict__ x, const float* __restrict__ tmx,
                          float* __restrict__ xx, unsigned short* __restrict__ xxx) {
  int idx = blockIdx.x * 256 + threadIdx.x;  // float4 groups, 2M total
  int c4 = idx & 255;
  int row = idx >> 8;
  int t = row & (TT - 1);
  const float4* x4 = (const float4*)x;
  float4 xv = x4[idx];
  float4 pv = make_float4(0.f, 0.f, 0.f, 0.f);
  if (t > 0) pv = x4[idx - 256];
  float4 d;
  d.x = pv.x - xv.x; d.y = pv.y - xv.y; d.z = pv.z - xv.z; d.w = pv.w - xv.w;
  ((float4*)xx)[idx] = d;
  float4 tm = ((const float4*)tmx)[c4];
  ushort4 o;
  o.x = f2b(xv.x + d.x * tm.x);
  o.y = f2b(xv.y + d.y * tm.y);
  o.z = f2b(xv.z + d.z * tm.z);
  o.w = f2b(xv.w + d.w * tm.w);
  ((ushort4*)xxx)[idx] = o;
}

// ---------------- bf16 MFMA GEMM, 128x128 tile, BK=32, global_load_lds staging -------
// A: [M,K] bf16 row-major (lda). Bt: [N,K] bf16 row-major (ldb) == B transposed.
// modes: 0 f32 store [row*ldc+col]; 1 tanh->bf16 [row*ldc+col];
//        2 gate: outB = bf16(x + xx*(tm[col]+acc)); 3 perm bf16 [B,H,T,16];
//        4 decay: outF[perm] = exp(-exp(tm[col]+acc))
__global__ __launch_bounds__(256) void gemm_bf16(
    const unsigned short* __restrict__ A, const unsigned short* __restrict__ Bt,
    int N, int K, int lda, int ldb, int mode, int ldc,
    float* __restrict__ outF, unsigned short* __restrict__ outB,
    const float* __restrict__ xg, const float* __restrict__ xxg,
    const float* __restrict__ tm) {
  __shared__ __align__(16) unsigned short As[4096];  // [kb(4)][m(128)][8]
  __shared__ __align__(16) unsigned short Bs[4096];
  int tid = threadIdx.x;
  int w = tid >> 6, lane = tid & 63;
  int quad = lane >> 4, l16 = lane & 15;
  int rowBase = blockIdx.y * 128;
  int colBase = blockIdx.x * 128;
  int waveM = (w >> 1) * 64, waveN = (w & 1) * 64;

  f32x4 acc[4][4];
#pragma unroll
  for (int i = 0; i < 4; i++)
#pragma unroll
    for (int j = 0; j < 4; j++) acc[i][j] = (f32x4){0.f, 0.f, 0.f, 0.f};

  for (int k0 = 0; k0 < K; k0 += 32) {
    __syncthreads();
#pragma unroll
    for (int i = 0; i < 2; i++) {
      int c = w * 2 + i;          // 0..7
      int kb = c >> 1;            // == w
      int mh = (c & 1) * 64;
      const unsigned short* ga = A + (size_t)(rowBase + mh + lane) * lda + k0 + kb * 8;
      gl_lds16(ga, (char*)As + (size_t)(kb * 128 + mh) * 16);
      const unsigned short* gb = Bt + (size_t)(colBase + mh + lane) * ldb + k0 + kb * 8;
      gl_lds16(gb, (char*)Bs + (size_t)(kb * 128 + mh) * 16);
    }
    __syncthreads();
    bf16x8 af[4], bfr[4];
#pragma unroll
    for (int mt = 0; mt < 4; mt++)
      af[mt] = *(const bf16x8*)(As + (size_t)(quad * 128 + waveM + mt * 16 + l16) * 8);
#pragma unroll
    for (int nt = 0; nt < 4; nt++)
      bfr[nt] = *(const bf16x8*)(Bs + (size_t)(quad * 128 + waveN + nt * 16 + l16) * 8);
#pragma unroll
    for (int mt = 0; mt < 4; mt++)
#pragma unroll
      for (int nt = 0; nt < 4; nt++)
        acc[mt][nt] = __builtin_amdgcn_mfma_f32_16x16x32_bf16(af[mt], bfr[nt], acc[mt][nt], 0, 0, 0);
  }

#pragma unroll
  for (int mt = 0; mt < 4; mt++) {
#pragma unroll
    for (int nt = 0; nt < 4; nt++) {
#pragma unroll
      for (int rg = 0; rg < 4; rg++) {
        int row = rowBase + waveM + mt * 16 + quad * 4 + rg;
        int col = colBase + waveN + nt * 16 + l16;
        if (col >= N) continue;
        float val = acc[mt][nt][rg];
        if (mode == 0) {
          outF[(size_t)row * ldc + col] = val;
        } else if (mode == 1) {
          outB[(size_t)row * ldc + col] = f2b(tanhf(val));
        } else if (mode == 2) {
          size_t o = (size_t)row * CC + col;
          outB[o] = f2b(xg[o] + xxg[o] * (tm[col] + val));
        } else if (mode == 3) {
          int b = row >> 11, t = row & (TT - 1), h = col >> 4, n = col & 15;
          outB[(size_t)((b * 64 + h) * TT + t) * 16 + n] = f2b(val);
        } else {
          int b = row >> 11, t = row & (TT - 1), h = col >> 4, n = col & 15;
          outF[(size_t)((b * 64 + h) * TT + t) * 16 + n] = expf(-expf(tm[col] + val));
        }
      }
    }
  }
}

// ---------------- WKV6 chunk-parallel scan ----------------
// One block (16 waves) per (b,h). Wave c owns chunk c of 128 steps.
// Pass A: local scan from S=0 -> Lend, decay product Eend (per row).
// Pass B: wave 0 sequentially combines: Sini[c+1] = Eend[c] (*) Sini[c] + Lend[c].
// Pass C: full scan per chunk from Sini[c], producing y.
// r,k,v: bf16 [B*H, T, 16]; wd: f32 [B*H, T, 16]; u: f32 [64,16]; y: f32 [B,T,C]
__global__ __launch_bounds__(1024) void wkv_scan2(
    const unsigned short* __restrict__ r, const unsigned short* __restrict__ k,
    const unsigned short* __restrict__ v, const float* __restrict__ wd,
    const float* __restrict__ u, float* __restrict__ y) {
  __shared__ __align__(16) float lr[16][256];
  __shared__ __align__(16) float lk[16][256];
  __shared__ __align__(16) float lv[16][256];
  __shared__ __align__(16) float lw[16][256];
  __shared__ __align__(16) float Lend[16][256];  // [c][i*16+j]
  __shared__ __align__(16) float Sini[16][256];  // [c][i*16+j]
  __shared__ float Eend[16][16];                 // [c][i]
  int bh = blockIdx.x;
  int b = bh >> 6, h = bh & 63;
  int tid = threadIdx.x;
  int c = tid >> 6, lane = tid & 63;
  int j = lane & 15, p = lane >> 4;  // lane owns rows p*4..p*4+3, col j
  size_t base = (size_t)bh * TT * 16 + (size_t)c * 128 * 16;

  // ---- Pass A: state-only local scan ----
  float S0 = 0.f, S1 = 0.f, S2 = 0.f, S3 = 0.f;
  float E0 = 1.f, E1 = 1.f, E2 = 1.f, E3 = 1.f;
  for (int t0 = 0; t0 < 128; t0 += 16) {
    size_t off = base + (size_t)t0 * 16;
    ushort4 kv4 = ((const ushort4*)(k + off))[lane];
    ushort4 vv = ((const ushort4*)(v + off))[lane];
    float4 wv = ((const float4*)(wd + off))[lane];
    ((float4*)lk[c])[lane] = make_float4(b2f(kv4.x), b2f(kv4.y), b2f(kv4.z), b2f(kv4.w));
    ((float4*)lv[c])[lane] = make_float4(b2f(vv.x), b2f(vv.y), b2f(vv.z), b2f(vv.w));
    ((float4*)lw[c])[lane] = wv;
    // buffers are wave-private; in-wave LDS ordering handled by compiler waits
#pragma unroll
    for (int s = 0; s < 16; s++) {
      float4 kk = *(const float4*)(lk[c] + s * 16 + p * 4);
      float4 ww = *(const float4*)(lw[c] + s * 16 + p * 4);
      float vj = lv[c][s * 16 + j];
      S0 = fmaf(ww.x, S0, kk.x * vj); E0 *= ww.x;
      S1 = fmaf(ww.y, S1, kk.y * vj); E1 *= ww.y;
      S2 = fmaf(ww.z, S2, kk.z * vj); E2 *= ww.z;
      S3 = fmaf(ww.w, S3, kk.w * vj); E3 *= ww.w;
    }
  }
  Lend[c][(p * 4 + 0) * 16 + j] = S0;
  Lend[c][(p * 4 + 1) * 16 + j] = S1;
  Lend[c][(p * 4 + 2) * 16 + j] = S2;
  Lend[c][(p * 4 + 3) * 16 + j] = S3;
  if (j == 0) {
    Eend[c][p * 4 + 0] = E0;
    Eend[c][p * 4 + 1] = E1;
    Eend[c][p * 4 + 2] = E2;
    Eend[c][p * 4 + 3] = E3;
  }
  __syncthreads();

  // ---- Pass B: sequential chunk combine (wave 0 only) ----
  if (c == 0) {
    float T0 = 0.f, T1 = 0.f, T2 = 0.f, T3 = 0.f;
    for (int cc = 0; cc < 16; cc++) {
      Sini[cc][(p * 4 + 0) * 16 + j] = T0;
      Sini[cc][(p * 4 + 1) * 16 + j] = T1;
      Sini[cc][(p * 4 + 2) * 16 + j] = T2;
      Sini[cc][(p * 4 + 3) * 16 + j] = T3;
      float e0 = Eend[cc][p * 4 + 0], e1 = Eend[cc][p * 4 + 1];
      float e2 = Eend[cc][p * 4 + 2], e3 = Eend[cc][p * 4 + 3];
      T0 = fmaf(e0, T0, Lend[cc][(p * 4 + 0) * 16 + j]);
      T1 = fmaf(e1, T1, Lend[cc][(p * 4 + 1) * 16 + j]);
      T2 = fmaf(e2, T2, Lend[cc][(p * 4 + 2) * 16 + j]);
      T3 = fmaf(e3, T3, Lend[cc][(p * 4 + 3) * 16 + j]);
    }
  }
  __syncthreads();

  // ---- Pass C: full scan with correct initial state ----
  float u0 = u[h * 16 + p * 4 + 0], u1 = u[h * 16 + p * 4 + 1];
  float u2 = u[h * 16 + p * 4 + 2], u3 = u[h * 16 + p * 4 + 3];
  S0 = Sini[c][(p * 4 + 0) * 16 + j];
  S1 = Sini[c][(p * 4 + 1) * 16 + j];
  S2 = Sini[c][(p * 4 + 2) * 16 + j];
  S3 = Sini[c][(p * 4 + 3) * 16 + j];
  for (int t0 = 0; t0 < 128; t0 += 16) {
    size_t off = base + (size_t)t0 * 16;
    ushort4 rv = ((const ushort4*)(r + off))[lane];
    ushort4 kv4 = ((const ushort4*)(k + off))[lane];
    ushort4 vv = ((const ushort4*)(v + off))[lane];
    float4 wv = ((const float4*)(wd + off))[lane];
    ((float4*)lr[c])[lane] = make_float4(b2f(rv.x), b2f(rv.y), b2f(rv.z), b2f(rv.w));
    ((float4*)lk[c])[lane] = make_float4(b2f(kv4.x), b2f(kv4.y), b2f(kv4.z), b2f(kv4.w));
    ((float4*)lv[c])[lane] = make_float4(b2f(vv.x), b2f(vv.y), b2f(vv.z), b2f(vv.w));
    ((float4*)lw[c])[lane] = wv;
#pragma unroll
    for (int s = 0; s < 16; s++) {
      float4 rr = *(const float4*)(lr[c] + s * 16 + p * 4);
      float4 kk = *(const float4*)(lk[c] + s * 16 + p * 4);
      float4 ww = *(const float4*)(lw[c] + s * 16 + p * 4);
      float vj = lv[c][s * 16 + j];
      float kv, part;
      kv = kk.x * vj; part = rr.x * fmaf(u0, kv, S0); S0 = fmaf(ww.x, S0, kv);
      kv = kk.y * vj; part = fmaf(rr.y, fmaf(u1, kv, S1), part); S1 = fmaf(ww.y, S1, kv);
      kv = kk.z * vj; part = fmaf(rr.z, fmaf(u2, kv, S2), part); S2 = fmaf(ww.z, S2, kv);
      kv = kk.w * vj; part = fmaf(rr.w, fmaf(u3, kv, S3), part); S3 = fmaf(ww.w, S3, kv);
      part += __shfl_xor(part, 16, 64);
      part += __shfl_xor(part, 32, 64);
      if (p == 0) y[(size_t)(b * TT + c * 128 + t0 + s) * CC + h * 16 + j] = part;
    }
  }
}

// ---------------- LayerNorm -> bf16 ----------------
__global__ __launch_bounds__(256) void ln_fused(const float* __restrict__ y,
                                                const float* __restrict__ g,
                                                const float* __restrict__ be,
                                                unsigned short* __restrict__ out) {
  int row = blockIdx.x;
  int tid = threadIdx.x;
  float4 val = ((const float4*)(y + (size_t)row * CC))[tid];
  float s = val.x + val.y + val.z + val.w;
  float sq = val.x * val.x + val.y * val.y + val.z * val.z + val.w * val.w;
#pragma unroll
  for (int m = 1; m < 64; m <<= 1) {
    s += __shfl_xor(s, m, 64);
    sq += __shfl_xor(sq, m, 64);
  }
  __shared__ float ss[4], s2[4];
  int w = tid >> 6;
  if ((tid & 63) == 0) { ss[w] = s; s2[w] = sq; }
  __syncthreads();
  s = ss[0] + ss[1] + ss[2] + ss[3];
  sq = s2[0] + s2[1] + s2[2] + s2[3];
  float mu = s * (1.f / 1024.f);
  float var = sq * (1.f / 1024.f) - mu * mu;
  float rstd = rsqrtf(var + 1e-5f);
  float4 gg = ((const float4*)g)[tid];
  float4 bb = ((const float4*)be)[tid];
  ushort4 o;
  o.x = f2b((val.x - mu) * rstd * gg.x + bb.x);
  o.y = f2b((val.y - mu) * rstd * gg.y + bb.y);
  o.z = f2b((val.z - mu) * rstd * gg.z + bb.z);
  o.w = f2b((val.w - mu) * rstd * gg.w + bb.w);
  ((ushort4*)(out + (size_t)row * CC))[tid] = o;
}

extern "C" void kernel_launch(void* const* d_in, const int* in_sizes, int n_in,
                              void* d_out, int out_size, void* d_ws, size_t ws_size,
                              hipStream_t stream) {
  (void)in_sizes; (void)n_in; (void)out_size; (void)ws_size;
  const float* x = (const float*)d_in[0];
  const float* tmx = (const float*)d_in[1];
  const float* tmw = (const float*)d_in[2];
  const float* tmk = (const float*)d_in[3];
  const float* tmv = (const float*)d_in[4];
  const float* tmr = (const float*)d_in[5];
  const float* w1 = (const float*)d_in[6];
  const float* w2 = (const float*)d_in[7];
  const float* tdecay = (const float*)d_in[8];
  const float* dw1 = (const float*)d_in[9];
  const float* dw2 = (const float*)d_in[10];
  const float* faaaa = (const float*)d_in[11];
  const float* Wr = (const float*)d_in[12];
  const float* Wk = (const float*)d_in[13];
  const float* Wv = (const float*)d_in[14];
  const float* Wo = (const float*)d_in[15];
  const float* lng = (const float*)d_in[16];
  const float* lnb = (const float*)d_in[17];
  float* out = (float*)d_out;

  char* ws = (char*)d_ws;
  const size_t MBy = 1ull << 20;
  unsigned short* rb = (unsigned short*)(ws + 0);          // 16MB  bf16 [BH,T,16]
  unsigned short* kbuf = (unsigned short*)(ws + 16 * MBy); // 16MB
  unsigned short* vbuf = (unsigned short*)(ws + 32 * MBy); // 16MB
  float* wdb = (float*)(ws + 48 * MBy);                    // 32MB  f32 [BH,T,16]
  float* xxb = (float*)(ws + 80 * MBy);                    // 32MB (dead after gates)
  float* yb = (float*)(ws + 80 * MBy);                     // 32MB (reuse)
  unsigned short* xxxb = (unsigned short*)(ws + 112 * MBy);// 16MB (dead after mix)
  unsigned short* xwb = (unsigned short*)(ws + 112 * MBy); // aliases xxx (dead)
  unsigned short* xrb = (unsigned short*)(ws + 128 * MBy);
  unsigned short* xkb = (unsigned short*)(ws + 144 * MBy);
  unsigned short* xvb = (unsigned short*)(ws + 160 * MBy);
  unsigned short* ynb = (unsigned short*)(ws + 144 * MBy); // reuse xk after k-GEMM
  unsigned short* mtmpb = (unsigned short*)(ws + 176 * MBy); // 2MB bf16 [8192,128]
  unsigned short* dtmpb = (unsigned short*)(ws + 178 * MBy); // 1MB bf16 [8192,64]
  char* wreg = ws + 180 * MBy;
  unsigned short* w1t = (unsigned short*)(wreg);               // [128,1024]
  unsigned short* w2t = (unsigned short*)(wreg + 256 * 1024);  // 4x[1024,32]
  unsigned short* dw1t = (unsigned short*)(wreg + 512 * 1024); // [64,1024]
  unsigned short* dw2t = (unsigned short*)(wreg + 640 * 1024); // [1024,64]
  unsigned short* Wrt = (unsigned short*)(wreg + 768 * 1024);  // [1024,1024]
  unsigned short* Wkt = Wrt + 1024 * 1024;
  unsigned short* Wvt = Wkt + 1024 * 1024;
  unsigned short* Wot = Wvt + 1024 * 1024;

  dim3 tb(32, 8);
  transpose_cvt<<<dim3(4, 32), tb, 0, stream>>>(w1, w1t, 1024, 128);
  for (int g = 0; g < 4; g++)
    transpose_cvt<<<dim3(32, 1), tb, 0, stream>>>(w2 + (size_t)g * 32 * 1024,
                                                  w2t + (size_t)g * 1024 * 32, 32, 1024);
  transpose_cvt<<<dim3(2, 32), tb, 0, stream>>>(dw1, dw1t, 1024, 64);
  transpose_cvt<<<dim3(32, 2), tb, 0, stream>>>(dw2, dw2t, 64, 1024);
  transpose_cvt<<<dim3(32, 32), tb, 0, stream>>>(Wr, Wrt, 1024, 1024);
  transpose_cvt<<<dim3(32, 32), tb, 0, stream>>>(Wk, Wkt, 1024, 1024);
  transpose_cvt<<<dim3(32, 32), tb, 0, stream>>>(Wv, Wvt, 1024, 1024);
  transpose_cvt<<<dim3(32, 32), tb, 0, stream>>>(Wo, Wot, 1024, 1024);

  shift_mix<<<8192, 256, 0, stream>>>(x, tmx, xxb, xxxb);

  // mixer: mtmp = tanh(xxx @ w1)  [8192,128]
  gemm_bf16<<<dim3(1, 64), 256, 0, stream>>>(xxxb, w1t, 128, 1024, 1024, 1024, 1, 128,
                                             nullptr, mtmpb, nullptr, nullptr, nullptr);
  // gates: xg = bf16(x + xx*(tm_g + mtmp[:,g] @ w2[g]))
  {
    const float* tms[4] = {tmw, tmk, tmv, tmr};
    unsigned short* xouts[4] = {xwb, xkb, xvb, xrb};
    for (int g = 0; g < 4; g++)
      gemm_bf16<<<dim3(8, 64), 256, 0, stream>>>(mtmpb + g * 32, w2t + (size_t)g * 1024 * 32,
                                                 1024, 32, 128, 32, 2, 1024,
                                                 nullptr, xouts[g], x, xxb, tms[g]);
  }
  // decay: dtmp = tanh(xw @ dw1); wd = exp(-exp(tdecay + dtmp @ dw2)) (permuted)
  gemm_bf16<<<dim3(1, 64), 256, 0, stream>>>(xwb, dw1t, 64, 1024, 1024, 1024, 1, 64,
                                             nullptr, dtmpb, nullptr, nullptr, nullptr);
  gemm_bf16<<<dim3(8, 64), 256, 0, stream>>>(dtmpb, dw2t, 1024, 64, 64, 64, 4, 1024,
                                             wdb, nullptr, nullptr, nullptr, tdecay);
  // projections (permuted bf16 [BH,T,16])
  gemm_bf16<<<dim3(8, 64), 256, 0, stream>>>(xrb, Wrt, 1024, 1024, 1024, 1024, 3, 1024,
                                             nullptr, rb, nullptr, nullptr, nullptr);
  gemm_bf16<<<dim3(8, 64), 256, 0, stream>>>(xkb, Wkt, 1024, 1024, 1024, 1024, 3, 1024,
                                             nullptr, kbuf, nullptr, nullptr, nullptr);
  gemm_bf16<<<dim3(8, 64), 256, 0, stream>>>(xvb, Wvt, 1024, 1024, 1024, 1024, 3, 1024,
                                             nullptr, vbuf, nullptr, nullptr, nullptr);

  wkv_scan2<<<256, 1024, 0, stream>>>(rb, kbuf, vbuf, wdb, faaaa, yb);
  ln_fused<<<8192, 256, 0, stream>>>(yb, lng, lnb, ynb);
  // out = ynorm @ W_o
  gemm_bf16<<<dim3(8, 64), 256, 0, stream>>>(ynb, Wot, 1024, 1024, 1024, 1024, 0, 1024,
                                             out, nullptr, nullptr, nullptr, nullptr);
}

// Round 3
// 527.142 us; speedup vs baseline: 1.6882x; 1.2355x over previous
//
#include <hip/hip_runtime.h>
#include <stdint.h>

#define TT 2048
#define CC 1024

typedef short bf16x8 __attribute__((ext_vector_type(8)));
typedef float f32x4 __attribute__((ext_vector_type(4)));
typedef __attribute__((address_space(3))) uint32_t lds_u32_t;
typedef const __attribute__((address_space(1))) uint32_t glb_u32_t;

__device__ inline unsigned short f2b(float f) {
  union { float f; unsigned u; } c; c.f = f;
  unsigned u = c.u;
  return (unsigned short)((u + 0x7fffu + ((u >> 16) & 1u)) >> 16);
}
__device__ inline float b2f(unsigned short s) {
  union { unsigned u; float f; } c; c.u = ((unsigned)s) << 16; return c.f;
}

__device__ inline void gl_lds16(const void* g, void* l) {
  glb_u32_t* gp = (glb_u32_t*)(uintptr_t)g;
  lds_u32_t* lp = (lds_u32_t*)(uint32_t)(uintptr_t)l;
  __builtin_amdgcn_global_load_lds(gp, lp, 16, 0, 0);
}

// ---------------- transpose + f32->bf16 convert: out[C,R] = in[R,C] ----------------
__global__ void transpose_cvt(const float* __restrict__ in, unsigned short* __restrict__ out,
                              int R, int C) {
  __shared__ float tile[32][33];
  int c0 = blockIdx.x * 32, r0 = blockIdx.y * 32;
  int tx = threadIdx.x, ty = threadIdx.y;  // 32x8
  for (int i = ty; i < 32; i += 8) {
    int r = r0 + i, c = c0 + tx;
    tile[i][tx] = (r < R && c < C) ? in[(size_t)r * C + c] : 0.f;
  }
  __syncthreads();
  int rr = r0 + tx;
  for (int i = ty; i < 32; i += 8) {
    int cc = c0 + i;
    if (cc < C && rr < R) out[(size_t)cc * R + rr] = f2b(tile[tx][i]);
  }
}

struct Trans4 { const float* in[4]; unsigned short* out[4]; int R, C; };
__global__ void transpose_cvt4(Trans4 a) {
  __shared__ float tile[32][33];
  int z = blockIdx.z;
  const float* in = a.in[z];
  unsigned short* out = a.out[z];
  int R = a.R, C = a.C;
  int c0 = blockIdx.x * 32, r0 = blockIdx.y * 32;
  int tx = threadIdx.x, ty = threadIdx.y;
  for (int i = ty; i < 32; i += 8) {
    int r = r0 + i, c = c0 + tx;
    tile[i][tx] = (r < R && c < C) ? in[(size_t)r * C + c] : 0.f;
  }
  __syncthreads();
  int rr = r0 + tx;
  for (int i = ty; i < 32; i += 8) {
    int cc = c0 + i;
    if (cc < C && rr < R) out[(size_t)cc * R + rr] = f2b(tile[tx][i]);
  }
}

// ---- token shift: xb=bf16(x); xxb=bf16(shift(x)-x); xxx=bf16(x + xx*tmx) ----
__global__ void shift_mix(const float* __restrict__ x, const float* __restrict__ tmx,
                          unsigned short* __restrict__ xb, unsigned short* __restrict__ xxb,
                          unsigned short* __restrict__ xxx) {
  int idx = blockIdx.x * 256 + threadIdx.x;  // float4 groups, 2M total
  int c4 = idx & 255;
  int row = idx >> 8;
  int t = row & (TT - 1);
  const float4* x4 = (const float4*)x;
  float4 xv = x4[idx];
  float4 pv = make_float4(0.f, 0.f, 0.f, 0.f);
  if (t > 0) pv = x4[idx - 256];
  float4 d;
  d.x = pv.x - xv.x; d.y = pv.y - xv.y; d.z = pv.z - xv.z; d.w = pv.w - xv.w;
  ushort4 ob;
  ob.x = f2b(xv.x); ob.y = f2b(xv.y); ob.z = f2b(xv.z); ob.w = f2b(xv.w);
  ((ushort4*)xb)[idx] = ob;
  ushort4 od;
  od.x = f2b(d.x); od.y = f2b(d.y); od.z = f2b(d.z); od.w = f2b(d.w);
  ((ushort4*)xxb)[idx] = od;
  float4 tm = ((const float4*)tmx)[c4];
  ushort4 o;
  o.x = f2b(xv.x + d.x * tm.x);
  o.y = f2b(xv.y + d.y * tm.y);
  o.z = f2b(xv.z + d.z * tm.z);
  o.w = f2b(xv.w + d.w * tm.w);
  ((ushort4*)xxx)[idx] = o;
}

// ---------------- shared MFMA core: 128x128 tile, BK=32 ----------------
__device__ __forceinline__ void gemm_core(
    const unsigned short* __restrict__ A, const unsigned short* __restrict__ Bt,
    int K, int lda, int ldb, int rowBase, int colBase,
    unsigned short* As, unsigned short* Bs, f32x4 acc[4][4], int w, int lane,
    int quad, int l16, int waveM, int waveN) {
#pragma unroll
  for (int i = 0; i < 4; i++)
#pragma unroll
    for (int j = 0; j < 4; j++) acc[i][j] = (f32x4){0.f, 0.f, 0.f, 0.f};
  for (int k0 = 0; k0 < K; k0 += 32) {
    __syncthreads();
#pragma unroll
    for (int i = 0; i < 2; i++) {
      int c = w * 2 + i;
      int kb = c >> 1;
      int mh = (c & 1) * 64;
      const unsigned short* ga = A + (size_t)(rowBase + mh + lane) * lda + k0 + kb * 8;
      gl_lds16(ga, (char*)As + (size_t)(kb * 128 + mh) * 16);
      const unsigned short* gb = Bt + (size_t)(colBase + mh + lane) * ldb + k0 + kb * 8;
      gl_lds16(gb, (char*)Bs + (size_t)(kb * 128 + mh) * 16);
    }
    __syncthreads();
    bf16x8 af[4], bfr[4];
#pragma unroll
    for (int mt = 0; mt < 4; mt++)
      af[mt] = *(const bf16x8*)(As + (size_t)(quad * 128 + waveM + mt * 16 + l16) * 8);
#pragma unroll
    for (int nt = 0; nt < 4; nt++)
      bfr[nt] = *(const bf16x8*)(Bs + (size_t)(quad * 128 + waveN + nt * 16 + l16) * 8);
#pragma unroll
    for (int mt = 0; mt < 4; mt++)
#pragma unroll
      for (int nt = 0; nt < 4; nt++)
        acc[mt][nt] = __builtin_amdgcn_mfma_f32_16x16x32_bf16(af[mt], bfr[nt], acc[mt][nt], 0, 0, 0);
  }
}

// ---------------- generic GEMM: modes 0 f32, 1 tanh->bf16, 4 decay perm ----------------
__global__ __launch_bounds__(256) void gemm_bf16(
    const unsigned short* __restrict__ A, const unsigned short* __restrict__ Bt,
    int N, int K, int lda, int ldb, int mode, int ldc,
    float* __restrict__ outF, unsigned short* __restrict__ outB,
    const float* __restrict__ tm) {
  __shared__ __align__(16) unsigned short As[4096];
  __shared__ __align__(16) unsigned short Bs[4096];
  int tid = threadIdx.x;
  int w = tid >> 6, lane = tid & 63;
  int quad = lane >> 4, l16 = lane & 15;
  int rowBase = blockIdx.y * 128;
  int colBase = blockIdx.x * 128;
  int waveM = (w >> 1) * 64, waveN = (w & 1) * 64;
  f32x4 acc[4][4];
  gemm_core(A, Bt, K, lda, ldb, rowBase, colBase, As, Bs, acc, w, lane, quad, l16, waveM, waveN);
#pragma unroll
  for (int mt = 0; mt < 4; mt++)
#pragma unroll
    for (int nt = 0; nt < 4; nt++)
#pragma unroll
      for (int rg = 0; rg < 4; rg++) {
        int row = rowBase + waveM + mt * 16 + quad * 4 + rg;
        int col = colBase + waveN + nt * 16 + l16;
        if (col >= N) continue;
        float val = acc[mt][nt][rg];
        if (mode == 0) {
          outF[(size_t)row * ldc + col] = val;
        } else if (mode == 1) {
          outB[(size_t)row * ldc + col] = f2b(tanhf(val));
        } else {
          int b = row >> 11, t = row & (TT - 1), h = col >> 4, n = col & 15;
          outF[(size_t)((b * 64 + h) * TT + t) * 16 + n] = expf(-expf(tm[col] + val));
        }
      }
}

// ---------------- batched gate GEMM: z selects gate; epilogue x + xx*(tm+acc) ----------------
struct GateArgs {
  const unsigned short* A;       // mtmp base [8192,128]
  const unsigned short* Bt;      // w2t base, 4 slices of [1024,32]
  unsigned short* out[4];
  const float* tm[4];
  const unsigned short* xb;
  const unsigned short* xxb;
};
__global__ __launch_bounds__(256) void gemm_gate4(GateArgs ga) {
  __shared__ __align__(16) unsigned short As[4096];
  __shared__ __align__(16) unsigned short Bs[4096];
  int z = blockIdx.z;
  const unsigned short* A = ga.A + z * 32;
  const unsigned short* Bt = ga.Bt + (size_t)z * 1024 * 32;
  unsigned short* outB = ga.out[z];
  const float* tm = ga.tm[z];
  int tid = threadIdx.x;
  int w = tid >> 6, lane = tid & 63;
  int quad = lane >> 4, l16 = lane & 15;
  int rowBase = blockIdx.y * 128;
  int colBase = blockIdx.x * 128;
  int waveM = (w >> 1) * 64, waveN = (w & 1) * 64;
  f32x4 acc[4][4];
  gemm_core(A, Bt, 32, 128, 32, rowBase, colBase, As, Bs, acc, w, lane, quad, l16, waveM, waveN);
#pragma unroll
  for (int mt = 0; mt < 4; mt++)
#pragma unroll
    for (int nt = 0; nt < 4; nt++)
#pragma unroll
      for (int rg = 0; rg < 4; rg++) {
        int row = rowBase + waveM + mt * 16 + quad * 4 + rg;
        int col = colBase + waveN + nt * 16 + l16;
        size_t o = (size_t)row * CC + col;
        float xv = b2f(ga.xb[o]), xxv = b2f(ga.xxb[o]);
        outB[o] = f2b(xv + xxv * (tm[col] + acc[mt][nt][rg]));
      }
}

// ---------------- batched projection GEMM: z selects (A,Bt,dst); perm bf16 store ----------------
struct ProjArgs {
  const unsigned short* A[3];
  const unsigned short* Bt[3];
  unsigned short* out[3];
};
__global__ __launch_bounds__(256) void gemm_proj3(ProjArgs pa) {
  __shared__ __align__(16) unsigned short As[4096];
  __shared__ __align__(16) unsigned short Bs[4096];
  int z = blockIdx.z;
  const unsigned short* A = pa.A[z];
  const unsigned short* Bt = pa.Bt[z];
  unsigned short* outB = pa.out[z];
  int tid = threadIdx.x;
  int w = tid >> 6, lane = tid & 63;
  int quad = lane >> 4, l16 = lane & 15;
  int rowBase = blockIdx.y * 128;
  int colBase = blockIdx.x * 128;
  int waveM = (w >> 1) * 64, waveN = (w & 1) * 64;
  f32x4 acc[4][4];
  gemm_core(A, Bt, 1024, 1024, 1024, rowBase, colBase, As, Bs, acc, w, lane, quad, l16, waveM, waveN);
#pragma unroll
  for (int mt = 0; mt < 4; mt++)
#pragma unroll
    for (int nt = 0; nt < 4; nt++)
#pragma unroll
      for (int rg = 0; rg < 4; rg++) {
        int row = rowBase + waveM + mt * 16 + quad * 4 + rg;
        int col = colBase + waveN + nt * 16 + l16;
        int b = row >> 11, t = row & (TT - 1), h = col >> 4, n = col & 15;
        outB[(size_t)((b * 64 + h) * TT + t) * 16 + n] = f2b(acc[mt][nt][rg]);
      }
}

// ---------------- WKV6 chunk-parallel scan (16 waves per (b,h)) ----------------
__global__ __launch_bounds__(1024) void wkv_scan2(
    const unsigned short* __restrict__ r, const unsigned short* __restrict__ k,
    const unsigned short* __restrict__ v, const float* __restrict__ wd,
    const float* __restrict__ u, float* __restrict__ y) {
  __shared__ __align__(16) float lr[16][256];
  __shared__ __align__(16) float lk[16][256];
  __shared__ __align__(16) float lv[16][256];
  __shared__ __align__(16) float lw[16][256];
  __shared__ __align__(16) float Lend[16][256];
  __shared__ __align__(16) float Sini[16][256];
  __shared__ float Eend[16][16];
  int bh = blockIdx.x;
  int b = bh >> 6, h = bh & 63;
  int tid = threadIdx.x;
  int c = tid >> 6, lane = tid & 63;
  int j = lane & 15, p = lane >> 4;
  size_t base = (size_t)bh * TT * 16 + (size_t)c * 128 * 16;

  float S0 = 0.f, S1 = 0.f, S2 = 0.f, S3 = 0.f;
  float E0 = 1.f, E1 = 1.f, E2 = 1.f, E3 = 1.f;
  for (int t0 = 0; t0 < 128; t0 += 16) {
    size_t off = base + (size_t)t0 * 16;
    ushort4 kv4 = ((const ushort4*)(k + off))[lane];
    ushort4 vv = ((const ushort4*)(v + off))[lane];
    float4 wv = ((const float4*)(wd + off))[lane];
    ((float4*)lk[c])[lane] = make_float4(b2f(kv4.x), b2f(kv4.y), b2f(kv4.z), b2f(kv4.w));
    ((float4*)lv[c])[lane] = make_float4(b2f(vv.x), b2f(vv.y), b2f(vv.z), b2f(vv.w));
    ((float4*)lw[c])[lane] = wv;
#pragma unroll
    for (int s = 0; s < 16; s++) {
      float4 kk = *(const float4*)(lk[c] + s * 16 + p * 4);
      float4 ww = *(const float4*)(lw[c] + s * 16 + p * 4);
      float vj = lv[c][s * 16 + j];
      S0 = fmaf(ww.x, S0, kk.x * vj); E0 *= ww.x;
      S1 = fmaf(ww.y, S1, kk.y * vj); E1 *= ww.y;
      S2 = fmaf(ww.z, S2, kk.z * vj); E2 *= ww.z;
      S3 = fmaf(ww.w, S3, kk.w * vj); E3 *= ww.w;
    }
  }
  Lend[c][(p * 4 + 0) * 16 + j] = S0;
  Lend[c][(p * 4 + 1) * 16 + j] = S1;
  Lend[c][(p * 4 + 2) * 16 + j] = S2;
  Lend[c][(p * 4 + 3) * 16 + j] = S3;
  if (j == 0) {
    Eend[c][p * 4 + 0] = E0;
    Eend[c][p * 4 + 1] = E1;
    Eend[c][p * 4 + 2] = E2;
    Eend[c][p * 4 + 3] = E3;
  }
  __syncthreads();

  if (c == 0) {
    float T0 = 0.f, T1 = 0.f, T2 = 0.f, T3 = 0.f;
    for (int cc = 0; cc < 16; cc++) {
      Sini[cc][(p * 4 + 0) * 16 + j] = T0;
      Sini[cc][(p * 4 + 1) * 16 + j] = T1;
      Sini[cc][(p * 4 + 2) * 16 + j] = T2;
      Sini[cc][(p * 4 + 3) * 16 + j] = T3;
      float e0 = Eend[cc][p * 4 + 0], e1 = Eend[cc][p * 4 + 1];
      float e2 = Eend[cc][p * 4 + 2], e3 = Eend[cc][p * 4 + 3];
      T0 = fmaf(e0, T0, Lend[cc][(p * 4 + 0) * 16 + j]);
      T1 = fmaf(e1, T1, Lend[cc][(p * 4 + 1) * 16 + j]);
      T2 = fmaf(e2, T2, Lend[cc][(p * 4 + 2) * 16 + j]);
      T3 = fmaf(e3, T3, Lend[cc][(p * 4 + 3) * 16 + j]);
    }
  }
  __syncthreads();

  float u0 = u[h * 16 + p * 4 + 0], u1 = u[h * 16 + p * 4 + 1];
  float u2 = u[h * 16 + p * 4 + 2], u3 = u[h * 16 + p * 4 + 3];
  S0 = Sini[c][(p * 4 + 0) * 16 + j];
  S1 = Sini[c][(p * 4 + 1) * 16 + j];
  S2 = Sini[c][(p * 4 + 2) * 16 + j];
  S3 = Sini[c][(p * 4 + 3) * 16 + j];
  for (int t0 = 0; t0 < 128; t0 += 16) {
    size_t off = base + (size_t)t0 * 16;
    ushort4 rv = ((const ushort4*)(r + off))[lane];
    ushort4 kv4 = ((const ushort4*)(k + off))[lane];
    ushort4 vv = ((const ushort4*)(v + off))[lane];
    float4 wv = ((const float4*)(wd + off))[lane];
    ((float4*)lr[c])[lane] = make_float4(b2f(rv.x), b2f(rv.y), b2f(rv.z), b2f(rv.w));
    ((float4*)lk[c])[lane] = make_float4(b2f(kv4.x), b2f(kv4.y), b2f(kv4.z), b2f(kv4.w));
    ((float4*)lv[c])[lane] = make_float4(b2f(vv.x), b2f(vv.y), b2f(vv.z), b2f(vv.w));
    ((float4*)lw[c])[lane] = wv;
#pragma unroll
    for (int s = 0; s < 16; s++) {
      float4 rr = *(const float4*)(lr[c] + s * 16 + p * 4);
      float4 kk = *(const float4*)(lk[c] + s * 16 + p * 4);
      float4 ww = *(const float4*)(lw[c] + s * 16 + p * 4);
      float vj = lv[c][s * 16 + j];
      float kv, part;
      kv = kk.x * vj; part = rr.x * fmaf(u0, kv, S0); S0 = fmaf(ww.x, S0, kv);
      kv = kk.y * vj; part = fmaf(rr.y, fmaf(u1, kv, S1), part); S1 = fmaf(ww.y, S1, kv);
      kv = kk.z * vj; part = fmaf(rr.z, fmaf(u2, kv, S2), part); S2 = fmaf(ww.z, S2, kv);
      kv = kk.w * vj; part = fmaf(rr.w, fmaf(u3, kv, S3), part); S3 = fmaf(ww.w, S3, kv);
      part += __shfl_xor(part, 16, 64);
      part += __shfl_xor(part, 32, 64);
      if (p == 0) y[(size_t)(b * TT + c * 128 + t0 + s) * CC + h * 16 + j] = part;
    }
  }
}

// ---------------- LayerNorm -> bf16 ----------------
__global__ __launch_bounds__(256) void ln_fused(const float* __restrict__ y,
                                                const float* __restrict__ g,
                                                const float* __restrict__ be,
                                                unsigned short* __restrict__ out) {
  int row = blockIdx.x;
  int tid = threadIdx.x;
  float4 val = ((const float4*)(y + (size_t)row * CC))[tid];
  float s = val.x + val.y + val.z + val.w;
  float sq = val.x * val.x + val.y * val.y + val.z * val.z + val.w * val.w;
#pragma unroll
  for (int m = 1; m < 64; m <<= 1) {
    s += __shfl_xor(s, m, 64);
    sq += __shfl_xor(sq, m, 64);
  }
  __shared__ float ss[4], s2[4];
  int w = tid >> 6;
  if ((tid & 63) == 0) { ss[w] = s; s2[w] = sq; }
  __syncthreads();
  s = ss[0] + ss[1] + ss[2] + ss[3];
  sq = s2[0] + s2[1] + s2[2] + s2[3];
  float mu = s * (1.f / 1024.f);
  float var = sq * (1.f / 1024.f) - mu * mu;
  float rstd = rsqrtf(var + 1e-5f);
  float4 gg = ((const float4*)g)[tid];
  float4 bb = ((const float4*)be)[tid];
  ushort4 o;
  o.x = f2b((val.x - mu) * rstd * gg.x + bb.x);
  o.y = f2b((val.y - mu) * rstd * gg.y + bb.y);
  o.z = f2b((val.z - mu) * rstd * gg.z + bb.z);
  o.w = f2b((val.w - mu) * rstd * gg.w + bb.w);
  ((ushort4*)(out + (size_t)row * CC))[tid] = o;
}

extern "C" void kernel_launch(void* const* d_in, const int* in_sizes, int n_in,
                              void* d_out, int out_size, void* d_ws, size_t ws_size,
                              hipStream_t stream) {
  (void)in_sizes; (void)n_in; (void)out_size; (void)ws_size;
  const float* x = (const float*)d_in[0];
  const float* tmx = (const float*)d_in[1];
  const float* tmw = (const float*)d_in[2];
  const float* tmk = (const float*)d_in[3];
  const float* tmv = (const float*)d_in[4];
  const float* tmr = (const float*)d_in[5];
  const float* w1 = (const float*)d_in[6];
  const float* w2 = (const float*)d_in[7];
  const float* tdecay = (const float*)d_in[8];
  const float* dw1 = (const float*)d_in[9];
  const float* dw2 = (const float*)d_in[10];
  const float* faaaa = (const float*)d_in[11];
  const float* Wr = (const float*)d_in[12];
  const float* Wk = (const float*)d_in[13];
  const float* Wv = (const float*)d_in[14];
  const float* Wo = (const float*)d_in[15];
  const float* lng = (const float*)d_in[16];
  const float* lnb = (const float*)d_in[17];
  float* out = (float*)d_out;

  char* ws = (char*)d_ws;
  const size_t MBy = 1ull << 20;
  unsigned short* rb   = (unsigned short*)(ws + 0);        // 16MB bf16 [BH,T,16]
  unsigned short* kbuf = (unsigned short*)(ws + 16 * MBy); // 16MB
  unsigned short* vbuf = (unsigned short*)(ws + 32 * MBy); // 16MB
  float* wdb = (float*)(ws + 48 * MBy);                    // 32MB f32 [BH,T,16]
  unsigned short* xb    = (unsigned short*)(ws + 80 * MBy);  // 16MB (dead after gates)
  unsigned short* xxb16 = (unsigned short*)(ws + 96 * MBy);  // 16MB (dead after gates)
  float* yb = (float*)(ws + 80 * MBy);                       // 32MB, aliases xb+xxb16
  unsigned short* xxxb = (unsigned short*)(ws + 112 * MBy);  // 16MB (dead after mixer)
  unsigned short* xwb  = (unsigned short*)(ws + 112 * MBy);  // aliases xxx
  unsigned short* xrb  = (unsigned short*)(ws + 128 * MBy);  // 16MB
  unsigned short* xkb  = (unsigned short*)(ws + 144 * MBy);  // 16MB (dead after proj)
  unsigned short* ynb  = (unsigned short*)(ws + 144 * MBy);  // aliases xkb
  unsigned short* xvb  = (unsigned short*)(ws + 160 * MBy);  // 16MB
  unsigned short* mtmpb = (unsigned short*)(ws + 176 * MBy); // 2MB bf16 [8192,128]
  unsigned short* dtmpb = (unsigned short*)(ws + 178 * MBy); // 1MB bf16 [8192,64]
  char* wreg = ws + 179 * MBy;
  unsigned short* w1t  = (unsigned short*)(wreg);               // [128,1024]
  unsigned short* w2t  = (unsigned short*)(wreg + 256 * 1024);  // 4x[1024,32]
  unsigned short* dw1t = (unsigned short*)(wreg + 512 * 1024);  // [64,1024]
  unsigned short* dw2t = (unsigned short*)(wreg + 640 * 1024);  // [1024,64]
  unsigned short* Wrt  = (unsigned short*)(wreg + 768 * 1024);  // [1024,1024]
  unsigned short* Wkt = Wrt + 1024 * 1024;
  unsigned short* Wvt = Wkt + 1024 * 1024;
  unsigned short* Wot = Wvt + 1024 * 1024;

  dim3 tb(32, 8);
  {
    Trans4 t4;
    t4.in[0] = Wr; t4.in[1] = Wk; t4.in[2] = Wv; t4.in[3] = Wo;
    t4.out[0] = Wrt; t4.out[1] = Wkt; t4.out[2] = Wvt; t4.out[3] = Wot;
    t4.R = 1024; t4.C = 1024;
    transpose_cvt4<<<dim3(32, 32, 4), tb, 0, stream>>>(t4);
  }
  {
    Trans4 t4;
    for (int g = 0; g < 4; g++) {
      t4.in[g] = w2 + (size_t)g * 32 * 1024;
      t4.out[g] = w2t + (size_t)g * 1024 * 32;
    }
    t4.R = 32; t4.C = 1024;
    transpose_cvt4<<<dim3(32, 1, 4), tb, 0, stream>>>(t4);
  }
  transpose_cvt<<<dim3(4, 32), tb, 0, stream>>>(w1, w1t, 1024, 128);
  transpose_cvt<<<dim3(2, 32), tb, 0, stream>>>(dw1, dw1t, 1024, 64);
  transpose_cvt<<<dim3(32, 2), tb, 0, stream>>>(dw2, dw2t, 64, 1024);

  shift_mix<<<8192, 256, 0, stream>>>(x, tmx, xb, xxb16, xxxb);

  // mixer: mtmp = tanh(xxx @ w1)  [8192,128]
  gemm_bf16<<<dim3(1, 64), 256, 0, stream>>>(xxxb, w1t, 128, 1024, 1024, 1024, 1, 128,
                                             nullptr, mtmpb, nullptr);
  // gates (batched): xg = bf16(x + xx*(tm_g + mtmp[:,g] @ w2[g]))
  {
    GateArgs ga;
    ga.A = mtmpb; ga.Bt = w2t;
    ga.out[0] = xwb; ga.out[1] = xkb; ga.out[2] = xvb; ga.out[3] = xrb;
    ga.tm[0] = tmw; ga.tm[1] = tmk; ga.tm[2] = tmv; ga.tm[3] = tmr;
    ga.xb = xb; ga.xxb = xxb16;
    gemm_gate4<<<dim3(8, 64, 4), 256, 0, stream>>>(ga);
  }
  // decay: dtmp = tanh(xw @ dw1); wd = exp(-exp(tdecay + dtmp @ dw2)) (permuted)
  gemm_bf16<<<dim3(1, 64), 256, 0, stream>>>(xwb, dw1t, 64, 1024, 1024, 1024, 1, 64,
                                             nullptr, dtmpb, nullptr);
  gemm_bf16<<<dim3(8, 64), 256, 0, stream>>>(dtmpb, dw2t, 1024, 64, 64, 64, 4, 1024,
                                             wdb, nullptr, tdecay);
  // projections (batched, permuted bf16 [BH,T,16])
  {
    ProjArgs pa;
    pa.A[0] = xrb; pa.A[1] = xkb; pa.A[2] = xvb;
    pa.Bt[0] = Wrt; pa.Bt[1] = Wkt; pa.Bt[2] = Wvt;
    pa.out[0] = rb; pa.out[1] = kbuf; pa.out[2] = vbuf;
    gemm_proj3<<<dim3(8, 64, 3), 256, 0, stream>>>(pa);
  }

  wkv_scan2<<<256, 1024, 0, stream>>>(rb, kbuf, vbuf, wdb, faaaa, yb);
  ln_fused<<<8192, 256, 0, stream>>>(yb, lng, lnb, ynb);
  // out = ynorm @ W_o
  gemm_bf16<<<dim3(8, 64), 256, 0, stream>>>(ynb, Wot, 1024, 1024, 1024, 1024, 0, 1024,
                                             out, nullptr, nullptr);
}

// Round 4
// 524.480 us; speedup vs baseline: 1.6968x; 1.0051x over previous
//
#include <hip/hip_runtime.h>
#include <stdint.h>

#define TT 2048
#define CC 1024

typedef short bf16x8 __attribute__((ext_vector_type(8)));
typedef float f32x4 __attribute__((ext_vector_type(4)));
typedef __attribute__((address_space(3))) uint32_t lds_u32_t;
typedef const __attribute__((address_space(1))) uint32_t glb_u32_t;

__device__ inline unsigned short f2b(float f) {
  union { float f; unsigned u; } c; c.f = f;
  unsigned u = c.u;
  return (unsigned short)((u + 0x7fffu + ((u >> 16) & 1u)) >> 16);
}
__device__ inline float b2f(unsigned short s) {
  union { unsigned u; float f; } c; c.u = ((unsigned)s) << 16; return c.f;
}

__device__ inline void gl_lds16(const void* g, void* l) {
  glb_u32_t* gp = (glb_u32_t*)(uintptr_t)g;
  lds_u32_t* lp = (lds_u32_t*)(uint32_t)(uintptr_t)l;
  __builtin_amdgcn_global_load_lds(gp, lp, 16, 0, 0);
}

// XCD-aware swizzle: consecutive blocks round-robin across 8 XCDs; give each
// XCD a contiguous band of row-tiles (cols fastest) so A-tiles stream through
// one XCD's L2 and B stays resident. Requires gridDim.y % 8 == 0.
__device__ inline void swiz(int& bx, int& by, int& bz) {
  int nx = gridDim.x, ny = gridDim.y;
  int flat = (blockIdx.z * ny + blockIdx.y) * nx + blockIdx.x;
  int xcd = flat & 7;
  int idx = flat >> 3;
  int perz = (nx * ny) >> 3;
  bz = idx / perz;
  int rem = idx - bz * perz;
  int r = rem / nx;
  bx = rem - r * nx;
  by = xcd * (ny >> 3) + r;
}

// ---------------- transpose + f32->bf16 convert: out[C,R] = in[R,C] ----------------
__global__ void transpose_cvt(const float* __restrict__ in, unsigned short* __restrict__ out,
                              int R, int C) {
  __shared__ float tile[32][33];
  int c0 = blockIdx.x * 32, r0 = blockIdx.y * 32;
  int tx = threadIdx.x, ty = threadIdx.y;  // 32x8
  for (int i = ty; i < 32; i += 8) {
    int r = r0 + i, c = c0 + tx;
    tile[i][tx] = (r < R && c < C) ? in[(size_t)r * C + c] : 0.f;
  }
  __syncthreads();
  int rr = r0 + tx;
  for (int i = ty; i < 32; i += 8) {
    int cc = c0 + i;
    if (cc < C && rr < R) out[(size_t)cc * R + rr] = f2b(tile[tx][i]);
  }
}

struct Trans4 { const float* in[4]; unsigned short* out[4]; int R, C; };
__global__ void transpose_cvt4(Trans4 a) {
  __shared__ float tile[32][33];
  int z = blockIdx.z;
  const float* in = a.in[z];
  unsigned short* out = a.out[z];
  int R = a.R, C = a.C;
  int c0 = blockIdx.x * 32, r0 = blockIdx.y * 32;
  int tx = threadIdx.x, ty = threadIdx.y;
  for (int i = ty; i < 32; i += 8) {
    int r = r0 + i, c = c0 + tx;
    tile[i][tx] = (r < R && c < C) ? in[(size_t)r * C + c] : 0.f;
  }
  __syncthreads();
  int rr = r0 + tx;
  for (int i = ty; i < 32; i += 8) {
    int cc = c0 + i;
    if (cc < C && rr < R) out[(size_t)cc * R + rr] = f2b(tile[tx][i]);
  }
}

// ---- token shift: xb=bf16(x); xxb=bf16(shift(x)-x); xxx=bf16(x + xx*tmx) ----
__global__ void shift_mix(const float* __restrict__ x, const float* __restrict__ tmx,
                          unsigned short* __restrict__ xb, unsigned short* __restrict__ xxb,
                          unsigned short* __restrict__ xxx) {
  int idx = blockIdx.x * 256 + threadIdx.x;  // float4 groups, 2M total
  int c4 = idx & 255;
  int row = idx >> 8;
  int t = row & (TT - 1);
  const float4* x4 = (const float4*)x;
  float4 xv = x4[idx];
  float4 pv = make_float4(0.f, 0.f, 0.f, 0.f);
  if (t > 0) pv = x4[idx - 256];
  float4 d;
  d.x = pv.x - xv.x; d.y = pv.y - xv.y; d.z = pv.z - xv.z; d.w = pv.w - xv.w;
  ushort4 ob;
  ob.x = f2b(xv.x); ob.y = f2b(xv.y); ob.z = f2b(xv.z); ob.w = f2b(xv.w);
  ((ushort4*)xb)[idx] = ob;
  ushort4 od;
  od.x = f2b(d.x); od.y = f2b(d.y); od.z = f2b(d.z); od.w = f2b(d.w);
  ((ushort4*)xxb)[idx] = od;
  float4 tm = ((const float4*)tmx)[c4];
  ushort4 o;
  o.x = f2b(xv.x + d.x * tm.x);
  o.y = f2b(xv.y + d.y * tm.y);
  o.z = f2b(xv.z + d.z * tm.z);
  o.w = f2b(xv.w + d.w * tm.w);
  ((ushort4*)xxx)[idx] = o;
}

// ---------------- shared MFMA core: 128x128 tile, BK=32 ----------------
__device__ __forceinline__ void gemm_core(
    const unsigned short* __restrict__ A, const unsigned short* __restrict__ Bt,
    int K, int lda, int ldb, int rowBase, int colBase,
    unsigned short* As, unsigned short* Bs, f32x4 acc[4][4], int w, int lane,
    int quad, int l16, int waveM, int waveN) {
#pragma unroll
  for (int i = 0; i < 4; i++)
#pragma unroll
    for (int j = 0; j < 4; j++) acc[i][j] = (f32x4){0.f, 0.f, 0.f, 0.f};
  for (int k0 = 0; k0 < K; k0 += 32) {
    __syncthreads();
#pragma unroll
    for (int i = 0; i < 2; i++) {
      int c = w * 2 + i;
      int kb = c >> 1;
      int mh = (c & 1) * 64;
      const unsigned short* ga = A + (size_t)(rowBase + mh + lane) * lda + k0 + kb * 8;
      gl_lds16(ga, (char*)As + (size_t)(kb * 128 + mh) * 16);
      const unsigned short* gb = Bt + (size_t)(colBase + mh + lane) * ldb + k0 + kb * 8;
      gl_lds16(gb, (char*)Bs + (size_t)(kb * 128 + mh) * 16);
    }
    __syncthreads();
    bf16x8 af[4], bfr[4];
#pragma unroll
    for (int mt = 0; mt < 4; mt++)
      af[mt] = *(const bf16x8*)(As + (size_t)(quad * 128 + waveM + mt * 16 + l16) * 8);
#pragma unroll
    for (int nt = 0; nt < 4; nt++)
      bfr[nt] = *(const bf16x8*)(Bs + (size_t)(quad * 128 + waveN + nt * 16 + l16) * 8);
#pragma unroll
    for (int mt = 0; mt < 4; mt++)
#pragma unroll
      for (int nt = 0; nt < 4; nt++)
        acc[mt][nt] = __builtin_amdgcn_mfma_f32_16x16x32_bf16(af[mt], bfr[nt], acc[mt][nt], 0, 0, 0);
  }
}

// ---------------- generic GEMM: modes 0 f32, 1 tanh->bf16, 4 decay perm ----------------
__global__ __launch_bounds__(256) void gemm_bf16(
    const unsigned short* __restrict__ A, const unsigned short* __restrict__ Bt,
    int N, int K, int lda, int ldb, int mode, int ldc,
    float* __restrict__ outF, unsigned short* __restrict__ outB,
    const float* __restrict__ tm) {
  __shared__ __align__(16) unsigned short As[4096];
  __shared__ __align__(16) unsigned short Bs[4096];
  int bx, by, bz;
  swiz(bx, by, bz);
  (void)bz;
  int tid = threadIdx.x;
  int w = tid >> 6, lane = tid & 63;
  int quad = lane >> 4, l16 = lane & 15;
  int rowBase = by * 128;
  int colBase = bx * 128;
  int waveM = (w >> 1) * 64, waveN = (w & 1) * 64;
  f32x4 acc[4][4];
  gemm_core(A, Bt, K, lda, ldb, rowBase, colBase, As, Bs, acc, w, lane, quad, l16, waveM, waveN);
#pragma unroll
  for (int mt = 0; mt < 4; mt++)
#pragma unroll
    for (int nt = 0; nt < 4; nt++)
#pragma unroll
      for (int rg = 0; rg < 4; rg++) {
        int row = rowBase + waveM + mt * 16 + quad * 4 + rg;
        int col = colBase + waveN + nt * 16 + l16;
        if (col >= N) continue;
        float val = acc[mt][nt][rg];
        if (mode == 0) {
          outF[(size_t)row * ldc + col] = val;
        } else if (mode == 1) {
          outB[(size_t)row * ldc + col] = f2b(tanhf(val));
        } else {
          int b = row >> 11, t = row & (TT - 1), h = col >> 4, n = col & 15;
          outF[(size_t)((b * 64 + h) * TT + t) * 16 + n] = expf(-expf(tm[col] + val));
        }
      }
}

// ---------------- batched gate GEMM: z-fastest swizzle; epilogue x + xx*(tm+acc) ----------------
struct GateArgs {
  const unsigned short* A;       // mtmp base [8192,128]
  const unsigned short* Bt;      // w2t base, 4 slices of [1024,32]
  unsigned short* out[4];
  const float* tm[4];
  const unsigned short* xb;
  const unsigned short* xxb;
};
__global__ __launch_bounds__(256) void gemm_gate4(GateArgs ga) {
  __shared__ __align__(16) unsigned short As[4096];
  __shared__ __align__(16) unsigned short Bs[4096];
  // custom swizzle: 4 gates of the same (row,col) tile consecutive on one XCD
  // so the xb/xxb patch is read once and hit in L2 three times.
  int flat = (blockIdx.z * 64 + blockIdx.y) * 8 + blockIdx.x;
  int xcd = flat & 7;
  int idx = flat >> 3;       // 0..255
  int z = idx & 3;
  int tile = idx >> 2;       // 0..63
  int by = xcd * 8 + (tile >> 3);
  int bx = tile & 7;
  const unsigned short* A = ga.A + z * 32;
  const unsigned short* Bt = ga.Bt + (size_t)z * 1024 * 32;
  unsigned short* outB = ga.out[z];
  const float* tm = ga.tm[z];
  int tid = threadIdx.x;
  int w = tid >> 6, lane = tid & 63;
  int quad = lane >> 4, l16 = lane & 15;
  int rowBase = by * 128;
  int colBase = bx * 128;
  int waveM = (w >> 1) * 64, waveN = (w & 1) * 64;
  f32x4 acc[4][4];
  gemm_core(A, Bt, 32, 128, 32, rowBase, colBase, As, Bs, acc, w, lane, quad, l16, waveM, waveN);
#pragma unroll
  for (int mt = 0; mt < 4; mt++)
#pragma unroll
    for (int nt = 0; nt < 4; nt++)
#pragma unroll
      for (int rg = 0; rg < 4; rg++) {
        int row = rowBase + waveM + mt * 16 + quad * 4 + rg;
        int col = colBase + waveN + nt * 16 + l16;
        size_t o = (size_t)row * CC + col;
        float xv = b2f(ga.xb[o]), xxv = b2f(ga.xxb[o]);
        outB[o] = f2b(xv + xxv * (tm[col] + acc[mt][nt][rg]));
      }
}

// ---------------- batched projection GEMM: z selects (A,Bt,dst); perm bf16 store ----------------
struct ProjArgs {
  const unsigned short* A[3];
  const unsigned short* Bt[3];
  unsigned short* out[3];
};
__global__ __launch_bounds__(256) void gemm_proj3(ProjArgs pa) {
  __shared__ __align__(16) unsigned short As[4096];
  __shared__ __align__(16) unsigned short Bs[4096];
  int bx, by, bz;
  swiz(bx, by, bz);
  const unsigned short* A = pa.A[bz];
  const unsigned short* Bt = pa.Bt[bz];
  unsigned short* outB = pa.out[bz];
  int tid = threadIdx.x;
  int w = tid >> 6, lane = tid & 63;
  int quad = lane >> 4, l16 = lane & 15;
  int rowBase = by * 128;
  int colBase = bx * 128;
  int waveM = (w >> 1) * 64, waveN = (w & 1) * 64;
  f32x4 acc[4][4];
  gemm_core(A, Bt, 1024, 1024, 1024, rowBase, colBase, As, Bs, acc, w, lane, quad, l16, waveM, waveN);
#pragma unroll
  for (int mt = 0; mt < 4; mt++)
#pragma unroll
    for (int nt = 0; nt < 4; nt++)
#pragma unroll
      for (int rg = 0; rg < 4; rg++) {
        int row = rowBase + waveM + mt * 16 + quad * 4 + rg;
        int col = colBase + waveN + nt * 16 + l16;
        int b = row >> 11, t = row & (TT - 1), h = col >> 4, n = col & 15;
        outB[(size_t)((b * 64 + h) * TT + t) * 16 + n] = f2b(acc[mt][nt][rg]);
      }
}

// ---------------- WKV6 chunk-parallel scan (16 waves per (b,h)) ----------------
__global__ __launch_bounds__(1024) void wkv_scan2(
    const unsigned short* __restrict__ r, const unsigned short* __restrict__ k,
    const unsigned short* __restrict__ v, const float* __restrict__ wd,
    const float* __restrict__ u, float* __restrict__ y) {
  __shared__ __align__(16) float lr[16][256];
  __shared__ __align__(16) float lk[16][256];
  __shared__ __align__(16) float lv[16][256];
  __shared__ __align__(16) float lw[16][256];
  __shared__ __align__(16) float Lend[16][256];
  __shared__ __align__(16) float Sini[16][256];
  __shared__ float Eend[16][16];
  int bh = blockIdx.x;
  int b = bh >> 6, h = bh & 63;
  int tid = threadIdx.x;
  int c = tid >> 6, lane = tid & 63;
  int j = lane & 15, p = lane >> 4;
  size_t base = (size_t)bh * TT * 16 + (size_t)c * 128 * 16;

  float S0 = 0.f, S1 = 0.f, S2 = 0.f, S3 = 0.f;
  float E0 = 1.f, E1 = 1.f, E2 = 1.f, E3 = 1.f;
  for (int t0 = 0; t0 < 128; t0 += 16) {
    size_t off = base + (size_t)t0 * 16;
    ushort4 kv4 = ((const ushort4*)(k + off))[lane];
    ushort4 vv = ((const ushort4*)(v + off))[lane];
    float4 wv = ((const float4*)(wd + off))[lane];
    ((float4*)lk[c])[lane] = make_float4(b2f(kv4.x), b2f(kv4.y), b2f(kv4.z), b2f(kv4.w));
    ((float4*)lv[c])[lane] = make_float4(b2f(vv.x), b2f(vv.y), b2f(vv.z), b2f(vv.w));
    ((float4*)lw[c])[lane] = wv;
#pragma unroll
    for (int s = 0; s < 16; s++) {
      float4 kk = *(const float4*)(lk[c] + s * 16 + p * 4);
      float4 ww = *(const float4*)(lw[c] + s * 16 + p * 4);
      float vj = lv[c][s * 16 + j];
      S0 = fmaf(ww.x, S0, kk.x * vj); E0 *= ww.x;
      S1 = fmaf(ww.y, S1, kk.y * vj); E1 *= ww.y;
      S2 = fmaf(ww.z, S2, kk.z * vj); E2 *= ww.z;
      S3 = fmaf(ww.w, S3, kk.w * vj); E3 *= ww.w;
    }
  }
  Lend[c][(p * 4 + 0) * 16 + j] = S0;
  Lend[c][(p * 4 + 1) * 16 + j] = S1;
  Lend[c][(p * 4 + 2) * 16 + j] = S2;
  Lend[c][(p * 4 + 3) * 16 + j] = S3;
  if (j == 0) {
    Eend[c][p * 4 + 0] = E0;
    Eend[c][p * 4 + 1] = E1;
    Eend[c][p * 4 + 2] = E2;
    Eend[c][p * 4 + 3] = E3;
  }
  __syncthreads();

  if (c == 0) {
    float T0 = 0.f, T1 = 0.f, T2 = 0.f, T3 = 0.f;
    for (int cc = 0; cc < 16; cc++) {
      Sini[cc][(p * 4 + 0) * 16 + j] = T0;
      Sini[cc][(p * 4 + 1) * 16 + j] = T1;
      Sini[cc][(p * 4 + 2) * 16 + j] = T2;
      Sini[cc][(p * 4 + 3) * 16 + j] = T3;
      float e0 = Eend[cc][p * 4 + 0], e1 = Eend[cc][p * 4 + 1];
      float e2 = Eend[cc][p * 4 + 2], e3 = Eend[cc][p * 4 + 3];
      T0 = fmaf(e0, T0, Lend[cc][(p * 4 + 0) * 16 + j]);
      T1 = fmaf(e1, T1, Lend[cc][(p * 4 + 1) * 16 + j]);
      T2 = fmaf(e2, T2, Lend[cc][(p * 4 + 2) * 16 + j]);
      T3 = fmaf(e3, T3, Lend[cc][(p * 4 + 3) * 16 + j]);
    }
  }
  __syncthreads();

  float u0 = u[h * 16 + p * 4 + 0], u1 = u[h * 16 + p * 4 + 1];
  float u2 = u[h * 16 + p * 4 + 2], u3 = u[h * 16 + p * 4 + 3];
  S0 = Sini[c][(p * 4 + 0) * 16 + j];
  S1 = Sini[c][(p * 4 + 1) * 16 + j];
  S2 = Sini[c][(p * 4 + 2) * 16 + j];
  S3 = Sini[c][(p * 4 + 3) * 16 + j];
  for (int t0 = 0; t0 < 128; t0 += 16) {
    size_t off = base + (size_t)t0 * 16;
    ushort4 rv = ((const ushort4*)(r + off))[lane];
    ushort4 kv4 = ((const ushort4*)(k + off))[lane];
    ushort4 vv = ((const ushort4*)(v + off))[lane];
    float4 wv = ((const float4*)(wd + off))[lane];
    ((float4*)lr[c])[lane] = make_float4(b2f(rv.x), b2f(rv.y), b2f(rv.z), b2f(rv.w));
    ((float4*)lk[c])[lane] = make_float4(b2f(kv4.x), b2f(kv4.y), b2f(kv4.z), b2f(kv4.w));
    ((float4*)lv[c])[lane] = make_float4(b2f(vv.x), b2f(vv.y), b2f(vv.z), b2f(vv.w));
    ((float4*)lw[c])[lane] = wv;
#pragma unroll
    for (int s = 0; s < 16; s++) {
      float4 rr = *(const float4*)(lr[c] + s * 16 + p * 4);
      float4 kk = *(const float4*)(lk[c] + s * 16 + p * 4);
      float4 ww = *(const float4*)(lw[c] + s * 16 + p * 4);
      float vj = lv[c][s * 16 + j];
      float kv, part;
      kv = kk.x * vj; part = rr.x * fmaf(u0, kv, S0); S0 = fmaf(ww.x, S0, kv);
      kv = kk.y * vj; part = fmaf(rr.y, fmaf(u1, kv, S1), part); S1 = fmaf(ww.y, S1, kv);
      kv = kk.z * vj; part = fmaf(rr.z, fmaf(u2, kv, S2), part); S2 = fmaf(ww.z, S2, kv);
      kv = kk.w * vj; part = fmaf(rr.w, fmaf(u3, kv, S3), part); S3 = fmaf(ww.w, S3, kv);
      part += __shfl_xor(part, 16, 64);
      part += __shfl_xor(part, 32, 64);
      if (p == 0) y[(size_t)(b * TT + c * 128 + t0 + s) * CC + h * 16 + j] = part;
    }
  }
}

// ---------------- LayerNorm -> bf16 ----------------
__global__ __launch_bounds__(256) void ln_fused(const float* __restrict__ y,
                                                const float* __restrict__ g,
                                                const float* __restrict__ be,
                                                unsigned short* __restrict__ out) {
  int row = blockIdx.x;
  int tid = threadIdx.x;
  float4 val = ((const float4*)(y + (size_t)row * CC))[tid];
  float s = val.x + val.y + val.z + val.w;
  float sq = val.x * val.x + val.y * val.y + val.z * val.z + val.w * val.w;
#pragma unroll
  for (int m = 1; m < 64; m <<= 1) {
    s += __shfl_xor(s, m, 64);
    sq += __shfl_xor(sq, m, 64);
  }
  __shared__ float ss[4], s2[4];
  int w = tid >> 6;
  if ((tid & 63) == 0) { ss[w] = s; s2[w] = sq; }
  __syncthreads();
  s = ss[0] + ss[1] + ss[2] + ss[3];
  sq = s2[0] + s2[1] + s2[2] + s2[3];
  float mu = s * (1.f / 1024.f);
  float var = sq * (1.f / 1024.f) - mu * mu;
  float rstd = rsqrtf(var + 1e-5f);
  float4 gg = ((const float4*)g)[tid];
  float4 bb = ((const float4*)be)[tid];
  ushort4 o;
  o.x = f2b((val.x - mu) * rstd * gg.x + bb.x);
  o.y = f2b((val.y - mu) * rstd * gg.y + bb.y);
  o.z = f2b((val.z - mu) * rstd * gg.z + bb.z);
  o.w = f2b((val.w - mu) * rstd * gg.w + bb.w);
  ((ushort4*)(out + (size_t)row * CC))[tid] = o;
}

extern "C" void kernel_launch(void* const* d_in, const int* in_sizes, int n_in,
                              void* d_out, int out_size, void* d_ws, size_t ws_size,
                              hipStream_t stream) {
  (void)in_sizes; (void)n_in; (void)out_size; (void)ws_size;
  const float* x = (const float*)d_in[0];
  const float* tmx = (const float*)d_in[1];
  const float* tmw = (const float*)d_in[2];
  const float* tmk = (const float*)d_in[3];
  const float* tmv = (const float*)d_in[4];
  const float* tmr = (const float*)d_in[5];
  const float* w1 = (const float*)d_in[6];
  const float* w2 = (const float*)d_in[7];
  const float* tdecay = (const float*)d_in[8];
  const float* dw1 = (const float*)d_in[9];
  const float* dw2 = (const float*)d_in[10];
  const float* faaaa = (const float*)d_in[11];
  const float* Wr = (const float*)d_in[12];
  const float* Wk = (const float*)d_in[13];
  const float* Wv = (const float*)d_in[14];
  const float* Wo = (const float*)d_in[15];
  const float* lng = (const float*)d_in[16];
  const float* lnb = (const float*)d_in[17];
  float* out = (float*)d_out;

  char* ws = (char*)d_ws;
  const size_t MBy = 1ull << 20;
  unsigned short* rb   = (unsigned short*)(ws + 0);        // 16MB bf16 [BH,T,16]
  unsigned short* kbuf = (unsigned short*)(ws + 16 * MBy); // 16MB
  unsigned short* vbuf = (unsigned short*)(ws + 32 * MBy); // 16MB
  float* wdb = (float*)(ws + 48 * MBy);                    // 32MB f32 [BH,T,16]
  unsigned short* xb    = (unsigned short*)(ws + 80 * MBy);  // 16MB (dead after gates)
  unsigned short* xxb16 = (unsigned short*)(ws + 96 * MBy);  // 16MB (dead after gates)
  float* yb = (float*)(ws + 80 * MBy);                       // 32MB, aliases xb+xxb16
  unsigned short* xxxb = (unsigned short*)(ws + 112 * MBy);  // 16MB (dead after mixer)
  unsigned short* xwb  = (unsigned short*)(ws + 112 * MBy);  // aliases xxx
  unsigned short* xrb  = (unsigned short*)(ws + 128 * MBy);  // 16MB
  unsigned short* xkb  = (unsigned short*)(ws + 144 * MBy);  // 16MB (dead after proj)
  unsigned short* ynb  = (unsigned short*)(ws + 144 * MBy);  // aliases xkb
  unsigned short* xvb  = (unsigned short*)(ws + 160 * MBy);  // 16MB
  unsigned short* mtmpb = (unsigned short*)(ws + 176 * MBy); // 2MB bf16 [8192,128]
  unsigned short* dtmpb = (unsigned short*)(ws + 178 * MBy); // 1MB bf16 [8192,64]
  char* wreg = ws + 179 * MBy;
  unsigned short* w1t  = (unsigned short*)(wreg);               // [128,1024]
  unsigned short* w2t  = (unsigned short*)(wreg + 256 * 1024);  // 4x[1024,32]
  unsigned short* dw1t = (unsigned short*)(wreg + 512 * 1024);  // [64,1024]
  unsigned short* dw2t = (unsigned short*)(wreg + 640 * 1024);  // [1024,64]
  unsigned short* Wrt  = (unsigned short*)(wreg + 768 * 1024);  // [1024,1024]
  unsigned short* Wkt = Wrt + 1024 * 1024;
  unsigned short* Wvt = Wkt + 1024 * 1024;
  unsigned short* Wot = Wvt + 1024 * 1024;

  dim3 tb(32, 8);
  {
    Trans4 t4;
    t4.in[0] = Wr; t4.in[1] = Wk; t4.in[2] = Wv; t4.in[3] = Wo;
    t4.out[0] = Wrt; t4.out[1] = Wkt; t4.out[2] = Wvt; t4.out[3] = Wot;
    t4.R = 1024; t4.C = 1024;
    transpose_cvt4<<<dim3(32, 32, 4), tb, 0, stream>>>(t4);
  }
  {
    Trans4 t4;
    for (int g = 0; g < 4; g++) {
      t4.in[g] = w2 + (size_t)g * 32 * 1024;
      t4.out[g] = w2t + (size_t)g * 1024 * 32;
    }
    t4.R = 32; t4.C = 1024;
    transpose_cvt4<<<dim3(32, 1, 4), tb, 0, stream>>>(t4);
  }
  transpose_cvt<<<dim3(4, 32), tb, 0, stream>>>(w1, w1t, 1024, 128);
  transpose_cvt<<<dim3(2, 32), tb, 0, stream>>>(dw1, dw1t, 1024, 64);
  transpose_cvt<<<dim3(32, 2), tb, 0, stream>>>(dw2, dw2t, 64, 1024);

  shift_mix<<<8192, 256, 0, stream>>>(x, tmx, xb, xxb16, xxxb);

  // mixer: mtmp = tanh(xxx @ w1)  [8192,128]
  gemm_bf16<<<dim3(1, 64), 256, 0, stream>>>(xxxb, w1t, 128, 1024, 1024, 1024, 1, 128,
                                             nullptr, mtmpb, nullptr);
  // gates (batched): xg = bf16(x + xx*(tm_g + mtmp[:,g] @ w2[g]))
  {
    GateArgs ga;
    ga.A = mtmpb; ga.Bt = w2t;
    ga.out[0] = xwb; ga.out[1] = xkb; ga.out[2] = xvb; ga.out[3] = xrb;
    ga.tm[0] = tmw; ga.tm[1] = tmk; ga.tm[2] = tmv; ga.tm[3] = tmr;
    ga.xb = xb; ga.xxb = xxb16;
    gemm_gate4<<<dim3(8, 64, 4), 256, 0, stream>>>(ga);
  }
  // decay: dtmp = tanh(xw @ dw1); wd = exp(-exp(tdecay + dtmp @ dw2)) (permuted)
  gemm_bf16<<<dim3(1, 64), 256, 0, stream>>>(xwb, dw1t, 64, 1024, 1024, 1024, 1, 64,
                                             nullptr, dtmpb, nullptr);
  gemm_bf16<<<dim3(8, 64), 256, 0, stream>>>(dtmpb, dw2t, 1024, 64, 64, 64, 4, 1024,
                                             wdb, nullptr, tdecay);
  // projections (batched, permuted bf16 [BH,T,16])
  {
    ProjArgs pa;
    pa.A[0] = xrb; pa.A[1] = xkb; pa.A[2] = xvb;
    pa.Bt[0] = Wrt; pa.Bt[1] = Wkt; pa.Bt[2] = Wvt;
    pa.out[0] = rb; pa.out[1] = kbuf; pa.out[2] = vbuf;
    gemm_proj3<<<dim3(8, 64, 3), 256, 0, stream>>>(pa);
  }

  wkv_scan2<<<256, 1024, 0, stream>>>(rb, kbuf, vbuf, wdb, faaaa, yb);
  ln_fused<<<8192, 256, 0, stream>>>(yb, lng, lnb, ynb);
  // out = ynorm @ W_o
  gemm_bf16<<<dim3(8, 64), 256, 0, stream>>>(ynb, Wot, 1024, 1024, 1024, 1024, 0, 1024,
                                             out, nullptr, nullptr);
}

// Round 5
// 458.036 us; speedup vs baseline: 1.9430x; 1.1451x over previous
//
#include <hip/hip_runtime.h>
#include <stdint.h>

#define TT 2048
#define CC 1024

typedef short bf16x8 __attribute__((ext_vector_type(8)));
typedef float f32x4 __attribute__((ext_vector_type(4)));
typedef __attribute__((address_space(3))) uint32_t lds_u32_t;
typedef const __attribute__((address_space(1))) uint32_t glb_u32_t;

__device__ inline unsigned short f2b(float f) {
  union { float f; unsigned u; } c; c.f = f;
  unsigned u = c.u;
  return (unsigned short)((u + 0x7fffu + ((u >> 16) & 1u)) >> 16);
}
__device__ inline float b2f(unsigned short s) {
  union { unsigned u; float f; } c; c.u = ((unsigned)s) << 16; return c.f;
}

__device__ inline void gl_lds16(const void* g, void* l) {
  glb_u32_t* gp = (glb_u32_t*)(uintptr_t)g;
  lds_u32_t* lp = (lds_u32_t*)(uint32_t)(uintptr_t)l;
  __builtin_amdgcn_global_load_lds(gp, lp, 16, 0, 0);
}

// XCD-aware swizzle (verified R3: FETCH 200->57MB on proj3). gridDim.y % 8 == 0.
__device__ inline void swiz(int& bx, int& by, int& bz) {
  int nx = gridDim.x, ny = gridDim.y;
  int flat = (blockIdx.z * ny + blockIdx.y) * nx + blockIdx.x;
  int xcd = flat & 7;
  int idx = flat >> 3;
  int perz = (nx * ny) >> 3;
  bz = idx / perz;
  int rem = idx - bz * perz;
  int r = rem / nx;
  bx = rem - r * nx;
  by = xcd * (ny >> 3) + r;
}

// ---------------- fused transposes: out[C,R] = bf16(in[R,C]), 11 segments ----------------
struct TSeg { const float* in; unsigned short* out; int R, C, tx, start; };
struct TransAll { TSeg seg[11]; int nseg; };
__global__ void transpose_all(TransAll ta) {
  __shared__ float tile[32][33];
  int bid = blockIdx.x;
  int si = 0;
  while (si + 1 < ta.nseg && bid >= ta.seg[si + 1].start) si++;
  TSeg sg = ta.seg[si];
  int lt = bid - sg.start;
  int bx = lt % sg.tx, by = lt / sg.tx;
  int c0 = bx * 32, r0 = by * 32;
  int tx = threadIdx.x, ty = threadIdx.y;  // 32x8
  for (int i = ty; i < 32; i += 8) {
    int r = r0 + i, c = c0 + tx;
    tile[i][tx] = (r < sg.R && c < sg.C) ? sg.in[(size_t)r * sg.C + c] : 0.f;
  }
  __syncthreads();
  int rr = r0 + tx;
  for (int i = ty; i < 32; i += 8) {
    int cc = c0 + i;
    if (cc < sg.C && rr < sg.R) sg.out[(size_t)cc * sg.R + rr] = f2b(tile[tx][i]);
  }
}

// ---- token shift: xb=bf16(x); xxb=bf16(shift(x)-x); xxx=bf16(x + xx*tmx) ----
__global__ void shift_mix(const float* __restrict__ x, const float* __restrict__ tmx,
                          unsigned short* __restrict__ xb, unsigned short* __restrict__ xxb,
                          unsigned short* __restrict__ xxx) {
  int idx = blockIdx.x * 256 + threadIdx.x;  // float4 groups, 2M total
  int c4 = idx & 255;
  int row = idx >> 8;
  int t = row & (TT - 1);
  const float4* x4 = (const float4*)x;
  float4 xv = x4[idx];
  float4 pv = make_float4(0.f, 0.f, 0.f, 0.f);
  if (t > 0) pv = x4[idx - 256];
  float4 d;
  d.x = pv.x - xv.x; d.y = pv.y - xv.y; d.z = pv.z - xv.z; d.w = pv.w - xv.w;
  ushort4 ob;
  ob.x = f2b(xv.x); ob.y = f2b(xv.y); ob.z = f2b(xv.z); ob.w = f2b(xv.w);
  ((ushort4*)xb)[idx] = ob;
  ushort4 od;
  od.x = f2b(d.x); od.y = f2b(d.y); od.z = f2b(d.z); od.w = f2b(d.w);
  ((ushort4*)xxb)[idx] = od;
  float4 tm = ((const float4*)tmx)[c4];
  ushort4 o;
  o.x = f2b(xv.x + d.x * tm.x);
  o.y = f2b(xv.y + d.y * tm.y);
  o.z = f2b(xv.z + d.z * tm.z);
  o.w = f2b(xv.w + d.w * tm.w);
  ((ushort4*)xxx)[idx] = o;
}

// ---------------- templated MFMA core: 128x128 tile, BK-deep LDS stage ----------------
// LDS layout: [BK/8][128][8] halves. As/Bs sized 128*BK each.
template <int BK>
__device__ __forceinline__ void gemm_core(
    const unsigned short* __restrict__ A, const unsigned short* __restrict__ Bt,
    int k0beg, int k0end, int lda, int ldb, int rowBase, int colBase,
    unsigned short* As, unsigned short* Bs, f32x4 acc[4][4], int w, int lane,
    int quad, int l16, int waveM, int waveN) {
#pragma unroll
  for (int i = 0; i < 4; i++)
#pragma unroll
    for (int j = 0; j < 4; j++) acc[i][j] = (f32x4){0.f, 0.f, 0.f, 0.f};
  constexpr int LPW = BK / 16;  // gl_lds16 per wave per matrix
  for (int k0 = k0beg; k0 < k0end; k0 += BK) {
    __syncthreads();
#pragma unroll
    for (int i = 0; i < LPW; i++) {
      int c = w * LPW + i;
      int kb = c >> 1;
      int mh = (c & 1) * 64;
      const unsigned short* ga = A + (size_t)(rowBase + mh + lane) * lda + k0 + kb * 8;
      gl_lds16(ga, (char*)As + (size_t)(kb * 128 + mh) * 16);
      const unsigned short* gb = Bt + (size_t)(colBase + mh + lane) * ldb + k0 + kb * 8;
      gl_lds16(gb, (char*)Bs + (size_t)(kb * 128 + mh) * 16);
    }
    __syncthreads();
#pragma unroll
    for (int s = 0; s < BK / 32; s++) {
      bf16x8 af[4], bfr[4];
#pragma unroll
      for (int mt = 0; mt < 4; mt++)
        af[mt] = *(const bf16x8*)(As + (size_t)((s * 4 + quad) * 128 + waveM + mt * 16 + l16) * 8);
#pragma unroll
      for (int nt = 0; nt < 4; nt++)
        bfr[nt] = *(const bf16x8*)(Bs + (size_t)((s * 4 + quad) * 128 + waveN + nt * 16 + l16) * 8);
#pragma unroll
      for (int mt = 0; mt < 4; mt++)
#pragma unroll
        for (int nt = 0; nt < 4; nt++)
          acc[mt][nt] = __builtin_amdgcn_mfma_f32_16x16x32_bf16(af[mt], bfr[nt], acc[mt][nt], 0, 0, 0);
    }
  }
}

// ---------------- generic GEMM (BK=64): modes 0 f32, 4 decay perm ----------------
__global__ __launch_bounds__(256) void gemm_bf16(
    const unsigned short* __restrict__ A, const unsigned short* __restrict__ Bt,
    int N, int K, int lda, int ldb, int mode, int ldc,
    float* __restrict__ outF, unsigned short* __restrict__ outB,
    const float* __restrict__ tm) {
  __shared__ __align__(16) unsigned short As[8192];
  __shared__ __align__(16) unsigned short Bs[8192];
  int bx, by, bz;
  swiz(bx, by, bz);
  (void)bz;
  int tid = threadIdx.x;
  int w = tid >> 6, lane = tid & 63;
  int quad = lane >> 4, l16 = lane & 15;
  int rowBase = by * 128;
  int colBase = bx * 128;
  int waveM = (w >> 1) * 64, waveN = (w & 1) * 64;
  f32x4 acc[4][4];
  gemm_core<64>(A, Bt, 0, K, lda, ldb, rowBase, colBase, As, Bs, acc, w, lane, quad, l16, waveM, waveN);
#pragma unroll
  for (int mt = 0; mt < 4; mt++)
#pragma unroll
    for (int nt = 0; nt < 4; nt++)
#pragma unroll
      for (int rg = 0; rg < 4; rg++) {
        int row = rowBase + waveM + mt * 16 + quad * 4 + rg;
        int col = colBase + waveN + nt * 16 + l16;
        if (col >= N) continue;
        float val = acc[mt][nt][rg];
        if (mode == 0) {
          outF[(size_t)row * ldc + col] = val;
        } else {
          int b = row >> 11, t = row & (TT - 1), h = col >> 4, n = col & 15;
          outF[(size_t)((b * 64 + h) * TT + t) * 16 + n] = expf(-expf(tm[col] + val));
        }
      }
}

// ---------------- split-K GEMM (BK=64): partials f32 [S][M][ldp] ----------------
__global__ __launch_bounds__(256) void gemm_splitk(
    const unsigned short* __restrict__ A, const unsigned short* __restrict__ Bt,
    int N, int Kc, int lda, int ldb, int ldp, float* __restrict__ part) {
  __shared__ __align__(16) unsigned short As[8192];
  __shared__ __align__(16) unsigned short Bs[8192];
  int s = blockIdx.x, by = blockIdx.y;
  int M = gridDim.y * 128;
  int tid = threadIdx.x;
  int w = tid >> 6, lane = tid & 63;
  int quad = lane >> 4, l16 = lane & 15;
  int rowBase = by * 128;
  int waveM = (w >> 1) * 64, waveN = (w & 1) * 64;
  f32x4 acc[4][4];
  gemm_core<64>(A, Bt, s * Kc, (s + 1) * Kc, lda, ldb, rowBase, 0, As, Bs, acc, w, lane, quad, l16, waveM, waveN);
  float* pb = part + (size_t)s * M * ldp;
#pragma unroll
  for (int mt = 0; mt < 4; mt++)
#pragma unroll
    for (int nt = 0; nt < 4; nt++)
#pragma unroll
      for (int rg = 0; rg < 4; rg++) {
        int row = rowBase + waveM + mt * 16 + quad * 4 + rg;
        int col = waveN + nt * 16 + l16;
        if (col < N) pb[(size_t)row * ldp + col] = acc[mt][nt][rg];
      }
}

// ---------------- reduce split-K partials + tanh -> bf16 ----------------
__global__ __launch_bounds__(256) void reduce_tanh(
    const float* __restrict__ part, unsigned short* __restrict__ out,
    int total4, int S, int strideElems) {
  int idx = blockIdx.x * 256 + threadIdx.x;
  if (idx >= total4) return;
  float4 a = ((const float4*)part)[idx];
  for (int s = 1; s < S; s++) {
    float4 b = ((const float4*)(part + (size_t)s * strideElems))[idx];
    a.x += b.x; a.y += b.y; a.z += b.z; a.w += b.w;
  }
  ushort4 o;
  o.x = f2b(tanhf(a.x)); o.y = f2b(tanhf(a.y));
  o.z = f2b(tanhf(a.z)); o.w = f2b(tanhf(a.w));
  ((ushort4*)out)[idx] = o;
}

// ---------------- batched gate GEMM (BK=32, K=32): epilogue x + xx*(tm+acc) ----------------
struct GateArgs {
  const unsigned short* A;
  const unsigned short* Bt;
  unsigned short* out[4];
  const float* tm[4];
  const unsigned short* xb;
  const unsigned short* xxb;
};
__global__ __launch_bounds__(256) void gemm_gate4(GateArgs ga) {
  __shared__ __align__(16) unsigned short As[4096];
  __shared__ __align__(16) unsigned short Bs[4096];
  // 4 gates of the same (row,col) tile consecutive on one XCD (xb/xxb L2 reuse)
  int flat = (blockIdx.z * 64 + blockIdx.y) * 8 + blockIdx.x;
  int xcd = flat & 7;
  int idx = flat >> 3;
  int z = idx & 3;
  int tile = idx >> 2;
  int by = xcd * 8 + (tile >> 3);
  int bx = tile & 7;
  const unsigned short* A = ga.A + z * 32;
  const unsigned short* Bt = ga.Bt + (size_t)z * 1024 * 32;
  unsigned short* outB = ga.out[z];
  const float* tm = ga.tm[z];
  int tid = threadIdx.x;
  int w = tid >> 6, lane = tid & 63;
  int quad = lane >> 4, l16 = lane & 15;
  int rowBase = by * 128;
  int colBase = bx * 128;
  int waveM = (w >> 1) * 64, waveN = (w & 1) * 64;
  f32x4 acc[4][4];
  gemm_core<32>(A, Bt, 0, 32, 128, 32, rowBase, colBase, As, Bs, acc, w, lane, quad, l16, waveM, waveN);
#pragma unroll
  for (int mt = 0; mt < 4; mt++)
#pragma unroll
    for (int nt = 0; nt < 4; nt++)
#pragma unroll
      for (int rg = 0; rg < 4; rg++) {
        int row = rowBase + waveM + mt * 16 + quad * 4 + rg;
        int col = colBase + waveN + nt * 16 + l16;
        size_t o = (size_t)row * CC + col;
        float xv = b2f(ga.xb[o]), xxv = b2f(ga.xxb[o]);
        outB[o] = f2b(xv + xxv * (tm[col] + acc[mt][nt][rg]));
      }
}

// ---------------- batched projection GEMM (BK=64): perm bf16 store ----------------
struct ProjArgs {
  const unsigned short* A[3];
  const unsigned short* Bt[3];
  unsigned short* out[3];
};
__global__ __launch_bounds__(256) void gemm_proj3(ProjArgs pa) {
  __shared__ __align__(16) unsigned short As[8192];
  __shared__ __align__(16) unsigned short Bs[8192];
  int bx, by, bz;
  swiz(bx, by, bz);
  const unsigned short* A = pa.A[bz];
  const unsigned short* Bt = pa.Bt[bz];
  unsigned short* outB = pa.out[bz];
  int tid = threadIdx.x;
  int w = tid >> 6, lane = tid & 63;
  int quad = lane >> 4, l16 = lane & 15;
  int rowBase = by * 128;
  int colBase = bx * 128;
  int waveM = (w >> 1) * 64, waveN = (w & 1) * 64;
  f32x4 acc[4][4];
  gemm_core<64>(A, Bt, 0, 1024, 1024, 1024, rowBase, colBase, As, Bs, acc, w, lane, quad, l16, waveM, waveN);
#pragma unroll
  for (int mt = 0; mt < 4; mt++)
#pragma unroll
    for (int nt = 0; nt < 4; nt++)
#pragma unroll
      for (int rg = 0; rg < 4; rg++) {
        int row = rowBase + waveM + mt * 16 + quad * 4 + rg;
        int col = colBase + waveN + nt * 16 + l16;
        int b = row >> 11, t = row & (TT - 1), h = col >> 4, n = col & 15;
        outB[(size_t)((b * 64 + h) * TT + t) * 16 + n] = f2b(acc[mt][nt][rg]);
      }
}

// ---------------- WKV6 chunk-parallel scan (16 waves per (b,h)) ----------------
__global__ __launch_bounds__(1024) void wkv_scan2(
    const unsigned short* __restrict__ r, const unsigned short* __restrict__ k,
    const unsigned short* __restrict__ v, const float* __restrict__ wd,
    const float* __restrict__ u, float* __restrict__ y) {
  __shared__ __align__(16) float lr[16][256];
  __shared__ __align__(16) float lk[16][256];
  __shared__ __align__(16) float lv[16][256];
  __shared__ __align__(16) float lw[16][256];
  __shared__ __align__(16) float Lend[16][256];
  __shared__ __align__(16) float Sini[16][256];
  __shared__ float Eend[16][16];
  int bh = blockIdx.x;
  int b = bh >> 6, h = bh & 63;
  int tid = threadIdx.x;
  int c = tid >> 6, lane = tid & 63;
  int j = lane & 15, p = lane >> 4;
  size_t base = (size_t)bh * TT * 16 + (size_t)c * 128 * 16;

  float S0 = 0.f, S1 = 0.f, S2 = 0.f, S3 = 0.f;
  float E0 = 1.f, E1 = 1.f, E2 = 1.f, E3 = 1.f;
  for (int t0 = 0; t0 < 128; t0 += 16) {
    size_t off = base + (size_t)t0 * 16;
    ushort4 kv4 = ((const ushort4*)(k + off))[lane];
    ushort4 vv = ((const ushort4*)(v + off))[lane];
    float4 wv = ((const float4*)(wd + off))[lane];
    ((float4*)lk[c])[lane] = make_float4(b2f(kv4.x), b2f(kv4.y), b2f(kv4.z), b2f(kv4.w));
    ((float4*)lv[c])[lane] = make_float4(b2f(vv.x), b2f(vv.y), b2f(vv.z), b2f(vv.w));
    ((float4*)lw[c])[lane] = wv;
#pragma unroll
    for (int s = 0; s < 16; s++) {
      float4 kk = *(const float4*)(lk[c] + s * 16 + p * 4);
      float4 ww = *(const float4*)(lw[c] + s * 16 + p * 4);
      float vj = lv[c][s * 16 + j];
      S0 = fmaf(ww.x, S0, kk.x * vj); E0 *= ww.x;
      S1 = fmaf(ww.y, S1, kk.y * vj); E1 *= ww.y;
      S2 = fmaf(ww.z, S2, kk.z * vj); E2 *= ww.z;
      S3 = fmaf(ww.w, S3, kk.w * vj); E3 *= ww.w;
    }
  }
  Lend[c][(p * 4 + 0) * 16 + j] = S0;
  Lend[c][(p * 4 + 1) * 16 + j] = S1;
  Lend[c][(p * 4 + 2) * 16 + j] = S2;
  Lend[c][(p * 4 + 3) * 16 + j] = S3;
  if (j == 0) {
    Eend[c][p * 4 + 0] = E0;
    Eend[c][p * 4 + 1] = E1;
    Eend[c][p * 4 + 2] = E2;
    Eend[c][p * 4 + 3] = E3;
  }
  __syncthreads();

  if (c == 0) {
    float T0 = 0.f, T1 = 0.f, T2 = 0.f, T3 = 0.f;
    for (int cc = 0; cc < 16; cc++) {
      Sini[cc][(p * 4 + 0) * 16 + j] = T0;
      Sini[cc][(p * 4 + 1) * 16 + j] = T1;
      Sini[cc][(p * 4 + 2) * 16 + j] = T2;
      Sini[cc][(p * 4 + 3) * 16 + j] = T3;
      float e0 = Eend[cc][p * 4 + 0], e1 = Eend[cc][p * 4 + 1];
      float e2 = Eend[cc][p * 4 + 2], e3 = Eend[cc][p * 4 + 3];
      T0 = fmaf(e0, T0, Lend[cc][(p * 4 + 0) * 16 + j]);
      T1 = fmaf(e1, T1, Lend[cc][(p * 4 + 1) * 16 + j]);
      T2 = fmaf(e2, T2, Lend[cc][(p * 4 + 2) * 16 + j]);
      T3 = fmaf(e3, T3, Lend[cc][(p * 4 + 3) * 16 + j]);
    }
  }
  __syncthreads();

  float u0 = u[h * 16 + p * 4 + 0], u1 = u[h * 16 + p * 4 + 1];
  float u2 = u[h * 16 + p * 4 + 2], u3 = u[h * 16 + p * 4 + 3];
  S0 = Sini[c][(p * 4 + 0) * 16 + j];
  S1 = Sini[c][(p * 4 + 1) * 16 + j];
  S2 = Sini[c][(p * 4 + 2) * 16 + j];
  S3 = Sini[c][(p * 4 + 3) * 16 + j];
  for (int t0 = 0; t0 < 128; t0 += 16) {
    size_t off = base + (size_t)t0 * 16;
    ushort4 rv = ((const ushort4*)(r + off))[lane];
    ushort4 kv4 = ((const ushort4*)(k + off))[lane];
    ushort4 vv = ((const ushort4*)(v + off))[lane];
    float4 wv = ((const float4*)(wd + off))[lane];
    ((float4*)lr[c])[lane] = make_float4(b2f(rv.x), b2f(rv.y), b2f(rv.z), b2f(rv.w));
    ((float4*)lk[c])[lane] = make_float4(b2f(kv4.x), b2f(kv4.y), b2f(kv4.z), b2f(kv4.w));
    ((float4*)lv[c])[lane] = make_float4(b2f(vv.x), b2f(vv.y), b2f(vv.z), b2f(vv.w));
    ((float4*)lw[c])[lane] = wv;
#pragma unroll
    for (int s = 0; s < 16; s++) {
      float4 rr = *(const float4*)(lr[c] + s * 16 + p * 4);
      float4 kk = *(const float4*)(lk[c] + s * 16 + p * 4);
      float4 ww = *(const float4*)(lw[c] + s * 16 + p * 4);
      float vj = lv[c][s * 16 + j];
      float kv, part;
      kv = kk.x * vj; part = rr.x * fmaf(u0, kv, S0); S0 = fmaf(ww.x, S0, kv);
      kv = kk.y * vj; part = fmaf(rr.y, fmaf(u1, kv, S1), part); S1 = fmaf(ww.y, S1, kv);
      kv = kk.z * vj; part = fmaf(rr.z, fmaf(u2, kv, S2), part); S2 = fmaf(ww.z, S2, kv);
      kv = kk.w * vj; part = fmaf(rr.w, fmaf(u3, kv, S3), part); S3 = fmaf(ww.w, S3, kv);
      part += __shfl_xor(part, 16, 64);
      part += __shfl_xor(part, 32, 64);
      if (p == 0) y[(size_t)(b * TT + c * 128 + t0 + s) * CC + h * 16 + j] = part;
    }
  }
}

// ---------------- LayerNorm -> bf16 ----------------
__global__ __launch_bounds__(256) void ln_fused(const float* __restrict__ y,
                                                const float* __restrict__ g,
                                                const float* __restrict__ be,
                                                unsigned short* __restrict__ out) {
  int row = blockIdx.x;
  int tid = threadIdx.x;
  float4 val = ((const float4*)(y + (size_t)row * CC))[tid];
  float s = val.x + val.y + val.z + val.w;
  float sq = val.x * val.x + val.y * val.y + val.z * val.z + val.w * val.w;
#pragma unroll
  for (int m = 1; m < 64; m <<= 1) {
    s += __shfl_xor(s, m, 64);
    sq += __shfl_xor(sq, m, 64);
  }
  __shared__ float ss[4], s2[4];
  int w = tid >> 6;
  if ((tid & 63) == 0) { ss[w] = s; s2[w] = sq; }
  __syncthreads();
  s = ss[0] + ss[1] + ss[2] + ss[3];
  sq = s2[0] + s2[1] + s2[2] + s2[3];
  float mu = s * (1.f / 1024.f);
  float var = sq * (1.f / 1024.f) - mu * mu;
  float rstd = rsqrtf(var + 1e-5f);
  float4 gg = ((const float4*)g)[tid];
  float4 bb = ((const float4*)be)[tid];
  ushort4 o;
  o.x = f2b((val.x - mu) * rstd * gg.x + bb.x);
  o.y = f2b((val.y - mu) * rstd * gg.y + bb.y);
  o.z = f2b((val.z - mu) * rstd * gg.z + bb.z);
  o.w = f2b((val.w - mu) * rstd * gg.w + bb.w);
  ((ushort4*)(out + (size_t)row * CC))[tid] = o;
}

extern "C" void kernel_launch(void* const* d_in, const int* in_sizes, int n_in,
                              void* d_out, int out_size, void* d_ws, size_t ws_size,
                              hipStream_t stream) {
  (void)in_sizes; (void)n_in; (void)out_size; (void)ws_size;
  const float* x = (const float*)d_in[0];
  const float* tmx = (const float*)d_in[1];
  const float* tmw = (const float*)d_in[2];
  const float* tmk = (const float*)d_in[3];
  const float* tmv = (const float*)d_in[4];
  const float* tmr = (const float*)d_in[5];
  const float* w1 = (const float*)d_in[6];
  const float* w2 = (const float*)d_in[7];
  const float* tdecay = (const float*)d_in[8];
  const float* dw1 = (const float*)d_in[9];
  const float* dw2 = (const float*)d_in[10];
  const float* faaaa = (const float*)d_in[11];
  const float* Wr = (const float*)d_in[12];
  const float* Wk = (const float*)d_in[13];
  const float* Wv = (const float*)d_in[14];
  const float* Wo = (const float*)d_in[15];
  const float* lng = (const float*)d_in[16];
  const float* lnb = (const float*)d_in[17];
  float* out = (float*)d_out;

  char* ws = (char*)d_ws;
  const size_t MBy = 1ull << 20;
  unsigned short* rb   = (unsigned short*)(ws + 0);        // 16MB bf16 [BH,T,16]
  unsigned short* kbuf = (unsigned short*)(ws + 16 * MBy); // 16MB
  unsigned short* vbuf = (unsigned short*)(ws + 32 * MBy); // 16MB
  float* wdb = (float*)(ws + 48 * MBy);                    // 32MB f32 [BH,T,16]
  unsigned short* xb    = (unsigned short*)(ws + 80 * MBy);  // 16MB (dead after gates)
  unsigned short* xxb16 = (unsigned short*)(ws + 96 * MBy);  // 16MB (dead after gates)
  float* yb = (float*)(ws + 80 * MBy);                       // 32MB, aliases xb+xxb16
  unsigned short* xxxb = (unsigned short*)(ws + 112 * MBy);  // 16MB (dead after mixer)
  unsigned short* xwb  = (unsigned short*)(ws + 112 * MBy);  // aliases xxx
  unsigned short* xrb  = (unsigned short*)(ws + 128 * MBy);  // 16MB
  unsigned short* xkb  = (unsigned short*)(ws + 144 * MBy);  // 16MB (dead after proj)
  unsigned short* ynb  = (unsigned short*)(ws + 144 * MBy);  // aliases xkb
  unsigned short* xvb  = (unsigned short*)(ws + 160 * MBy);  // 16MB
  // split-K partial scratch, placed in regions dead at their use time:
  float* mixP  = (float*)(ws + 128 * MBy);  // 16MB f32 [4][8192][128]; xrb written later
  float* decP  = (float*)(ws + 0);          // 8MB  f32 [4][8192][64];  rb written later
  unsigned short* mtmpb = (unsigned short*)(ws + 176 * MBy); // 2MB bf16 [8192,128]
  unsigned short* dtmpb = (unsigned short*)(ws + 178 * MBy); // 1MB bf16 [8192,64]
  char* wreg = ws + 179 * MBy;
  unsigned short* w1t  = (unsigned short*)(wreg);               // [128,1024]
  unsigned short* w2t  = (unsigned short*)(wreg + 256 * 1024);  // 4x[1024,32]
  unsigned short* dw1t = (unsigned short*)(wreg + 512 * 1024);  // [64,1024] (+pad reads ok)
  unsigned short* dw2t = (unsigned short*)(wreg + 768 * 1024);  // [1024,64]
  unsigned short* Wrt  = (unsigned short*)(wreg + 1024 * 1024); // [1024,1024]
  unsigned short* Wkt = Wrt + 1024 * 1024;
  unsigned short* Wvt = Wkt + 1024 * 1024;
  unsigned short* Wot = Wvt + 1024 * 1024;

  dim3 tb(32, 8);
  {
    TransAll ta;
    int st = 0, si = 0;
    auto add = [&](const float* in, unsigned short* o, int R, int C) {
      int tx = (C + 31) / 32, ty = (R + 31) / 32;
      ta.seg[si++] = TSeg{in, o, R, C, tx, st};
      st += tx * ty;
    };
    add(Wr, Wrt, 1024, 1024);
    add(Wk, Wkt, 1024, 1024);
    add(Wv, Wvt, 1024, 1024);
    add(Wo, Wot, 1024, 1024);
    for (int g = 0; g < 4; g++)
      add(w2 + (size_t)g * 32 * 1024, w2t + (size_t)g * 1024 * 32, 32, 1024);
    add(w1, w1t, 1024, 128);
    add(dw1, dw1t, 1024, 64);
    add(dw2, dw2t, 64, 1024);
    ta.nseg = si;
    transpose_all<<<st, tb, 0, stream>>>(ta);
  }

  shift_mix<<<8192, 256, 0, stream>>>(x, tmx, xb, xxb16, xxxb);

  // mixer: mtmp = tanh(xxx @ w1) via split-K(4)
  gemm_splitk<<<dim3(4, 64), 256, 0, stream>>>(xxxb, w1t, 128, 256, 1024, 1024, 128, mixP);
  reduce_tanh<<<1024, 256, 0, stream>>>(mixP, mtmpb, 8192 * 128 / 4, 4, 8192 * 128);

  // gates (batched): xg = bf16(x + xx*(tm_g + mtmp[:,g] @ w2[g]))
  {
    GateArgs ga;
    ga.A = mtmpb; ga.Bt = w2t;
    ga.out[0] = xwb; ga.out[1] = xkb; ga.out[2] = xvb; ga.out[3] = xrb;
    ga.tm[0] = tmw; ga.tm[1] = tmk; ga.tm[2] = tmv; ga.tm[3] = tmr;
    ga.xb = xb; ga.xxb = xxb16;
    gemm_gate4<<<dim3(8, 64, 4), 256, 0, stream>>>(ga);
  }
  // decay: dtmp = tanh(xw @ dw1) via split-K(4); wd = exp(-exp(tdecay + dtmp @ dw2))
  gemm_splitk<<<dim3(4, 64), 256, 0, stream>>>(xwb, dw1t, 64, 256, 1024, 1024, 64, decP);
  reduce_tanh<<<512, 256, 0, stream>>>(decP, dtmpb, 8192 * 64 / 4, 4, 8192 * 64);
  gemm_bf16<<<dim3(8, 64), 256, 0, stream>>>(dtmpb, dw2t, 1024, 64, 64, 64, 4, 1024,
                                             wdb, nullptr, tdecay);
  // projections (batched, permuted bf16 [BH,T,16])
  {
    ProjArgs pa;
    pa.A[0] = xrb; pa.A[1] = xkb; pa.A[2] = xvb;
    pa.Bt[0] = Wrt; pa.Bt[1] = Wkt; pa.Bt[2] = Wvt;
    pa.out[0] = rb; pa.out[1] = kbuf; pa.out[2] = vbuf;
    gemm_proj3<<<dim3(8, 64, 3), 256, 0, stream>>>(pa);
  }

  wkv_scan2<<<256, 1024, 0, stream>>>(rb, kbuf, vbuf, wdb, faaaa, yb);
  ln_fused<<<8192, 256, 0, stream>>>(yb, lng, lnb, ynb);
  // out = ynorm @ W_o
  gemm_bf16<<<dim3(8, 64), 256, 0, stream>>>(ynb, Wot, 1024, 1024, 1024, 1024, 0, 1024,
                                             out, nullptr, nullptr);
}

// Round 6
// 441.987 us; speedup vs baseline: 2.0135x; 1.0363x over previous
//
#include <hip/hip_runtime.h>
#include <stdint.h>

#define TT 2048
#define CC 1024

typedef short bf16x8 __attribute__((ext_vector_type(8)));
typedef float f32x4 __attribute__((ext_vector_type(4)));
typedef __attribute__((address_space(3))) uint32_t lds_u32_t;
typedef const __attribute__((address_space(1))) uint32_t glb_u32_t;

__device__ inline unsigned short f2b(float f) {
  union { float f; unsigned u; } c; c.f = f;
  unsigned u = c.u;
  return (unsigned short)((u + 0x7fffu + ((u >> 16) & 1u)) >> 16);
}
__device__ inline float b2f(unsigned short s) {
  union { unsigned u; float f; } c; c.u = ((unsigned)s) << 16; return c.f;
}

__device__ inline void gl_lds16(const void* g, void* l) {
  glb_u32_t* gp = (glb_u32_t*)(uintptr_t)g;
  lds_u32_t* lp = (lds_u32_t*)(uint32_t)(uintptr_t)l;
  __builtin_amdgcn_global_load_lds(gp, lp, 16, 0, 0);
}

// XCD-aware swizzle (verified R3: FETCH 200->57MB on proj3). gridDim.y % 8 == 0.
__device__ inline void swiz(int& bx, int& by, int& bz) {
  int nx = gridDim.x, ny = gridDim.y;
  int flat = (blockIdx.z * ny + blockIdx.y) * nx + blockIdx.x;
  int xcd = flat & 7;
  int idx = flat >> 3;
  int perz = (nx * ny) >> 3;
  bz = idx / perz;
  int rem = idx - bz * perz;
  int r = rem / nx;
  bx = rem - r * nx;
  by = xcd * (ny >> 3) + r;
}

// ---------------- fused transposes: out[C,R] = bf16(in[R,C]), 11 segments ----------------
struct TSeg { const float* in; unsigned short* out; int R, C, tx, start; };
struct TransAll { TSeg seg[11]; int nseg; };
__global__ void transpose_all(TransAll ta) {
  __shared__ float tile[32][33];
  int bid = blockIdx.x;
  int si = 0;
  while (si + 1 < ta.nseg && bid >= ta.seg[si + 1].start) si++;
  TSeg sg = ta.seg[si];
  int lt = bid - sg.start;
  int bx = lt % sg.tx, by = lt / sg.tx;
  int c0 = bx * 32, r0 = by * 32;
  int tx = threadIdx.x, ty = threadIdx.y;  // 32x8
  for (int i = ty; i < 32; i += 8) {
    int r = r0 + i, c = c0 + tx;
    tile[i][tx] = (r < sg.R && c < sg.C) ? sg.in[(size_t)r * sg.C + c] : 0.f;
  }
  __syncthreads();
  int rr = r0 + tx;
  for (int i = ty; i < 32; i += 8) {
    int cc = c0 + i;
    if (cc < sg.C && rr < sg.R) sg.out[(size_t)cc * sg.R + rr] = f2b(tile[tx][i]);
  }
}

// ---- token shift: xb=bf16(x); xxb=bf16(shift(x)-x); xxx=bf16(x + xx*tmx) ----
__global__ void shift_mix(const float* __restrict__ x, const float* __restrict__ tmx,
                          unsigned short* __restrict__ xb, unsigned short* __restrict__ xxb,
                          unsigned short* __restrict__ xxx) {
  int idx = blockIdx.x * 256 + threadIdx.x;  // float4 groups, 2M total
  int c4 = idx & 255;
  int row = idx >> 8;
  int t = row & (TT - 1);
  const float4* x4 = (const float4*)x;
  float4 xv = x4[idx];
  float4 pv = make_float4(0.f, 0.f, 0.f, 0.f);
  if (t > 0) pv = x4[idx - 256];
  float4 d;
  d.x = pv.x - xv.x; d.y = pv.y - xv.y; d.z = pv.z - xv.z; d.w = pv.w - xv.w;
  ushort4 ob;
  ob.x = f2b(xv.x); ob.y = f2b(xv.y); ob.z = f2b(xv.z); ob.w = f2b(xv.w);
  ((ushort4*)xb)[idx] = ob;
  ushort4 od;
  od.x = f2b(d.x); od.y = f2b(d.y); od.z = f2b(d.z); od.w = f2b(d.w);
  ((ushort4*)xxb)[idx] = od;
  float4 tm = ((const float4*)tmx)[c4];
  ushort4 o;
  o.x = f2b(xv.x + d.x * tm.x);
  o.y = f2b(xv.y + d.y * tm.y);
  o.z = f2b(xv.z + d.z * tm.z);
  o.w = f2b(xv.w + d.w * tm.w);
  ((ushort4*)xxx)[idx] = o;
}

// ---------------- pipelined MFMA core: 128x128 tile, BK=32, 3 LDS stages ----------------
// One raw s_barrier per K-iter; s_waitcnt vmcnt(4) keeps next tile's loads in
// flight across the barrier (AITER-style; __syncthreads' vmcnt(0) drain was the
// R3/R4 18%-MfmaUtil stall). Stage buffers: As/Bs = 3 * 128*32 shorts each.
__device__ __forceinline__ void gemm_core_pipe(
    const unsigned short* __restrict__ A, const unsigned short* __restrict__ Bt,
    int k0beg, int k0end, int lda, int ldb, int rowBase, int colBase,
    unsigned short* As, unsigned short* Bs, f32x4 acc[4][4], int w, int lane,
    int quad, int l16, int waveM, int waveN) {
#pragma unroll
  for (int i = 0; i < 4; i++)
#pragma unroll
    for (int j = 0; j < 4; j++) acc[i][j] = (f32x4){0.f, 0.f, 0.f, 0.f};
  const int SS = 128 * 32;  // shorts per stage
  const int nIter = (k0end - k0beg) >> 5;
  // per wave per tile: 2 A + 2 B gl_lds16 (kb = w, mh = 0/64)
  const unsigned short* gaBase = A + (size_t)(rowBase + lane) * lda + w * 8;
  const unsigned short* gbBase = Bt + (size_t)(colBase + lane) * ldb + w * 8;
  size_t a64 = (size_t)64 * lda, b64 = (size_t)64 * ldb;
  char* lA = (char*)As + (size_t)(w * 128) * 16;
  char* lB = (char*)Bs + (size_t)(w * 128) * 16;

#define ISSUE(it, stage)                                                      \
  {                                                                           \
    int k0 = k0beg + (it) * 32;                                               \
    gl_lds16(gaBase + k0, lA + (size_t)(stage) * SS * 2);                     \
    gl_lds16(gaBase + a64 + k0, lA + (size_t)(stage) * SS * 2 + 64 * 16);     \
    gl_lds16(gbBase + k0, lB + (size_t)(stage) * SS * 2);                     \
    gl_lds16(gbBase + b64 + k0, lB + (size_t)(stage) * SS * 2 + 64 * 16);     \
  }

  ISSUE(0, 0)
  if (nIter > 1) ISSUE(1, 1)
  int stage = 0;
  for (int it = 0; it < nIter; ++it) {
    if (it + 1 < nIter) {
      asm volatile("s_waitcnt vmcnt(4)\ns_barrier" ::: "memory");
    } else {
      asm volatile("s_waitcnt vmcnt(0)\ns_barrier" ::: "memory");
    }
    if (it + 2 < nIter) {
      int ns = stage + 2; if (ns >= 3) ns -= 3;
      ISSUE(it + 2, ns)
    }
    const unsigned short* Asb = As + stage * SS;
    const unsigned short* Bsb = Bs + stage * SS;
    bf16x8 af[4], bfr[4];
#pragma unroll
    for (int mt = 0; mt < 4; mt++)
      af[mt] = *(const bf16x8*)(Asb + (size_t)(quad * 128 + waveM + mt * 16 + l16) * 8);
#pragma unroll
    for (int nt = 0; nt < 4; nt++)
      bfr[nt] = *(const bf16x8*)(Bsb + (size_t)(quad * 128 + waveN + nt * 16 + l16) * 8);
#pragma unroll
    for (int mt = 0; mt < 4; mt++)
#pragma unroll
      for (int nt = 0; nt < 4; nt++)
        acc[mt][nt] = __builtin_amdgcn_mfma_f32_16x16x32_bf16(af[mt], bfr[nt], acc[mt][nt], 0, 0, 0);
    stage = stage + 1; if (stage >= 3) stage -= 3;
  }
#undef ISSUE
}

// ---------------- non-pipelined BK=32 core (gate4 only, K=32) ----------------
__device__ __forceinline__ void gemm_core32(
    const unsigned short* __restrict__ A, const unsigned short* __restrict__ Bt,
    int lda, int ldb, int rowBase, int colBase,
    unsigned short* As, unsigned short* Bs, f32x4 acc[4][4], int w, int lane,
    int quad, int l16, int waveM, int waveN) {
#pragma unroll
  for (int i = 0; i < 4; i++)
#pragma unroll
    for (int j = 0; j < 4; j++) acc[i][j] = (f32x4){0.f, 0.f, 0.f, 0.f};
#pragma unroll
  for (int i = 0; i < 2; i++) {
    int c = w * 2 + i;
    int kb = c >> 1;
    int mh = (c & 1) * 64;
    gl_lds16(A + (size_t)(rowBase + mh + lane) * lda + kb * 8,
             (char*)As + (size_t)(kb * 128 + mh) * 16);
    gl_lds16(Bt + (size_t)(colBase + mh + lane) * ldb + kb * 8,
             (char*)Bs + (size_t)(kb * 128 + mh) * 16);
  }
  __syncthreads();
  bf16x8 af[4], bfr[4];
#pragma unroll
  for (int mt = 0; mt < 4; mt++)
    af[mt] = *(const bf16x8*)(As + (size_t)(quad * 128 + waveM + mt * 16 + l16) * 8);
#pragma unroll
  for (int nt = 0; nt < 4; nt++)
    bfr[nt] = *(const bf16x8*)(Bs + (size_t)(quad * 128 + waveN + nt * 16 + l16) * 8);
#pragma unroll
  for (int mt = 0; mt < 4; mt++)
#pragma unroll
    for (int nt = 0; nt < 4; nt++)
      acc[mt][nt] = __builtin_amdgcn_mfma_f32_16x16x32_bf16(af[mt], bfr[nt], acc[mt][nt], 0, 0, 0);
}

// ---------------- generic GEMM (pipelined): modes 0 f32, 4 decay perm ----------------
__global__ __launch_bounds__(256) void gemm_bf16(
    const unsigned short* __restrict__ A, const unsigned short* __restrict__ Bt,
    int N, int K, int lda, int ldb, int mode, int ldc,
    float* __restrict__ outF, unsigned short* __restrict__ outB,
    const float* __restrict__ tm) {
  __shared__ __align__(16) unsigned short As[3 * 4096];
  __shared__ __align__(16) unsigned short Bs[3 * 4096];
  int bx, by, bz;
  swiz(bx, by, bz);
  (void)bz;
  int tid = threadIdx.x;
  int w = tid >> 6, lane = tid & 63;
  int quad = lane >> 4, l16 = lane & 15;
  int rowBase = by * 128;
  int colBase = bx * 128;
  int waveM = (w >> 1) * 64, waveN = (w & 1) * 64;
  f32x4 acc[4][4];
  gemm_core_pipe(A, Bt, 0, K, lda, ldb, rowBase, colBase, As, Bs, acc, w, lane, quad, l16, waveM, waveN);
#pragma unroll
  for (int mt = 0; mt < 4; mt++)
#pragma unroll
    for (int nt = 0; nt < 4; nt++)
#pragma unroll
      for (int rg = 0; rg < 4; rg++) {
        int row = rowBase + waveM + mt * 16 + quad * 4 + rg;
        int col = colBase + waveN + nt * 16 + l16;
        if (col >= N) continue;
        float val = acc[mt][nt][rg];
        if (mode == 0) {
          outF[(size_t)row * ldc + col] = val;
        } else {
          int b = row >> 11, t = row & (TT - 1), h = col >> 4, n = col & 15;
          outF[(size_t)((b * 64 + h) * TT + t) * 16 + n] = expf(-expf(tm[col] + val));
        }
      }
}

// ---------------- split-K GEMM (pipelined): partials f32 [S][M][ldp] ----------------
__global__ __launch_bounds__(256) void gemm_splitk(
    const unsigned short* __restrict__ A, const unsigned short* __restrict__ Bt,
    int N, int Kc, int lda, int ldb, int ldp, float* __restrict__ part) {
  __shared__ __align__(16) unsigned short As[3 * 4096];
  __shared__ __align__(16) unsigned short Bs[3 * 4096];
  int s = blockIdx.x, by = blockIdx.y;
  int M = gridDim.y * 128;
  int tid = threadIdx.x;
  int w = tid >> 6, lane = tid & 63;
  int quad = lane >> 4, l16 = lane & 15;
  int rowBase = by * 128;
  int waveM = (w >> 1) * 64, waveN = (w & 1) * 64;
  f32x4 acc[4][4];
  gemm_core_pipe(A, Bt, s * Kc, (s + 1) * Kc, lda, ldb, rowBase, 0, As, Bs, acc, w, lane, quad, l16, waveM, waveN);
  float* pb = part + (size_t)s * M * ldp;
#pragma unroll
  for (int mt = 0; mt < 4; mt++)
#pragma unroll
    for (int nt = 0; nt < 4; nt++)
#pragma unroll
      for (int rg = 0; rg < 4; rg++) {
        int row = rowBase + waveM + mt * 16 + quad * 4 + rg;
        int col = waveN + nt * 16 + l16;
        if (col < N) pb[(size_t)row * ldp + col] = acc[mt][nt][rg];
      }
}

// ---------------- reduce split-K partials + tanh -> bf16 ----------------
__global__ __launch_bounds__(256) void reduce_tanh(
    const float* __restrict__ part, unsigned short* __restrict__ out,
    int total4, int S, int strideElems) {
  int idx = blockIdx.x * 256 + threadIdx.x;
  if (idx >= total4) return;
  float4 a = ((const float4*)part)[idx];
  for (int s = 1; s < S; s++) {
    float4 b = ((const float4*)(part + (size_t)s * strideElems))[idx];
    a.x += b.x; a.y += b.y; a.z += b.z; a.w += b.w;
  }
  ushort4 o;
  o.x = f2b(tanhf(a.x)); o.y = f2b(tanhf(a.y));
  o.z = f2b(tanhf(a.z)); o.w = f2b(tanhf(a.w));
  ((ushort4*)out)[idx] = o;
}

// ---------------- batched gate GEMM (K=32): epilogue x + xx*(tm+acc) ----------------
struct GateArgs {
  const unsigned short* A;
  const unsigned short* Bt;
  unsigned short* out[4];
  const float* tm[4];
  const unsigned short* xb;
  const unsigned short* xxb;
};
__global__ __launch_bounds__(256) void gemm_gate4(GateArgs ga) {
  __shared__ __align__(16) unsigned short As[4096];
  __shared__ __align__(16) unsigned short Bs[4096];
  // 4 gates of the same (row,col) tile consecutive on one XCD (xb/xxb L2 reuse)
  int flat = (blockIdx.z * 64 + blockIdx.y) * 8 + blockIdx.x;
  int xcd = flat & 7;
  int idx = flat >> 3;
  int z = idx & 3;
  int tile = idx >> 2;
  int by = xcd * 8 + (tile >> 3);
  int bx = tile & 7;
  const unsigned short* A = ga.A + z * 32;
  const unsigned short* Bt = ga.Bt + (size_t)z * 1024 * 32;
  unsigned short* outB = ga.out[z];
  const float* tm = ga.tm[z];
  int tid = threadIdx.x;
  int w = tid >> 6, lane = tid & 63;
  int quad = lane >> 4, l16 = lane & 15;
  int rowBase = by * 128;
  int colBase = bx * 128;
  int waveM = (w >> 1) * 64, waveN = (w & 1) * 64;
  f32x4 acc[4][4];
  gemm_core32(A, Bt, 128, 32, rowBase, colBase, As, Bs, acc, w, lane, quad, l16, waveM, waveN);
#pragma unroll
  for (int mt = 0; mt < 4; mt++)
#pragma unroll
    for (int nt = 0; nt < 4; nt++)
#pragma unroll
      for (int rg = 0; rg < 4; rg++) {
        int row = rowBase + waveM + mt * 16 + quad * 4 + rg;
        int col = colBase + waveN + nt * 16 + l16;
        size_t o = (size_t)row * CC + col;
        float xv = b2f(ga.xb[o]), xxv = b2f(ga.xxb[o]);
        outB[o] = f2b(xv + xxv * (tm[col] + acc[mt][nt][rg]));
      }
}

// ---------------- batched projection GEMM (pipelined): perm bf16 store ----------------
struct ProjArgs {
  const unsigned short* A[3];
  const unsigned short* Bt[3];
  unsigned short* out[3];
};
__global__ __launch_bounds__(256) void gemm_proj3(ProjArgs pa) {
  __shared__ __align__(16) unsigned short As[3 * 4096];
  __shared__ __align__(16) unsigned short Bs[3 * 4096];
  int bx, by, bz;
  swiz(bx, by, bz);
  const unsigned short* A = pa.A[bz];
  const unsigned short* Bt = pa.Bt[bz];
  unsigned short* outB = pa.out[bz];
  int tid = threadIdx.x;
  int w = tid >> 6, lane = tid & 63;
  int quad = lane >> 4, l16 = lane & 15;
  int rowBase = by * 128;
  int colBase = bx * 128;
  int waveM = (w >> 1) * 64, waveN = (w & 1) * 64;
  f32x4 acc[4][4];
  gemm_core_pipe(A, Bt, 0, 1024, 1024, 1024, rowBase, colBase, As, Bs, acc, w, lane, quad, l16, waveM, waveN);
#pragma unroll
  for (int mt = 0; mt < 4; mt++)
#pragma unroll
    for (int nt = 0; nt < 4; nt++)
#pragma unroll
      for (int rg = 0; rg < 4; rg++) {
        int row = rowBase + waveM + mt * 16 + quad * 4 + rg;
        int col = colBase + waveN + nt * 16 + l16;
        int b = row >> 11, t = row & (TT - 1), h = col >> 4, n = col & 15;
        outB[(size_t)((b * 64 + h) * TT + t) * 16 + n] = f2b(acc[mt][nt][rg]);
      }
}

// ---------------- WKV6 chunk-parallel scan (16 waves per (b,h)) ----------------
__global__ __launch_bounds__(1024) void wkv_scan2(
    const unsigned short* __restrict__ r, const unsigned short* __restrict__ k,
    const unsigned short* __restrict__ v, const float* __restrict__ wd,
    const float* __restrict__ u, float* __restrict__ y) {
  __shared__ __align__(16) float lr[16][256];
  __shared__ __align__(16) float lk[16][256];
  __shared__ __align__(16) float lv[16][256];
  __shared__ __align__(16) float lw[16][256];
  __shared__ __align__(16) float Lend[16][256];
  __shared__ __align__(16) float Sini[16][256];
  __shared__ float Eend[16][16];
  int bh = blockIdx.x;
  int b = bh >> 6, h = bh & 63;
  int tid = threadIdx.x;
  int c = tid >> 6, lane = tid & 63;
  int j = lane & 15, p = lane >> 4;
  size_t base = (size_t)bh * TT * 16 + (size_t)c * 128 * 16;

  float S0 = 0.f, S1 = 0.f, S2 = 0.f, S3 = 0.f;
  float E0 = 1.f, E1 = 1.f, E2 = 1.f, E3 = 1.f;
  for (int t0 = 0; t0 < 128; t0 += 16) {
    size_t off = base + (size_t)t0 * 16;
    ushort4 kv4 = ((const ushort4*)(k + off))[lane];
    ushort4 vv = ((const ushort4*)(v + off))[lane];
    float4 wv = ((const float4*)(wd + off))[lane];
    ((float4*)lk[c])[lane] = make_float4(b2f(kv4.x), b2f(kv4.y), b2f(kv4.z), b2f(kv4.w));
    ((float4*)lv[c])[lane] = make_float4(b2f(vv.x), b2f(vv.y), b2f(vv.z), b2f(vv.w));
    ((float4*)lw[c])[lane] = wv;
#pragma unroll
    for (int s = 0; s < 16; s++) {
      float4 kk = *(const float4*)(lk[c] + s * 16 + p * 4);
      float4 ww = *(const float4*)(lw[c] + s * 16 + p * 4);
      float vj = lv[c][s * 16 + j];
      S0 = fmaf(ww.x, S0, kk.x * vj); E0 *= ww.x;
      S1 = fmaf(ww.y, S1, kk.y * vj); E1 *= ww.y;
      S2 = fmaf(ww.z, S2, kk.z * vj); E2 *= ww.z;
      S3 = fmaf(ww.w, S3, kk.w * vj); E3 *= ww.w;
    }
  }
  Lend[c][(p * 4 + 0) * 16 + j] = S0;
  Lend[c][(p * 4 + 1) * 16 + j] = S1;
  Lend[c][(p * 4 + 2) * 16 + j] = S2;
  Lend[c][(p * 4 + 3) * 16 + j] = S3;
  if (j == 0) {
    Eend[c][p * 4 + 0] = E0;
    Eend[c][p * 4 + 1] = E1;
    Eend[c][p * 4 + 2] = E2;
    Eend[c][p * 4 + 3] = E3;
  }
  __syncthreads();

  if (c == 0) {
    float T0 = 0.f, T1 = 0.f, T2 = 0.f, T3 = 0.f;
    for (int cc = 0; cc < 16; cc++) {
      Sini[cc][(p * 4 + 0) * 16 + j] = T0;
      Sini[cc][(p * 4 + 1) * 16 + j] = T1;
      Sini[cc][(p * 4 + 2) * 16 + j] = T2;
      Sini[cc][(p * 4 + 3) * 16 + j] = T3;
      float e0 = Eend[cc][p * 4 + 0], e1 = Eend[cc][p * 4 + 1];
      float e2 = Eend[cc][p * 4 + 2], e3 = Eend[cc][p * 4 + 3];
      T0 = fmaf(e0, T0, Lend[cc][(p * 4 + 0) * 16 + j]);
      T1 = fmaf(e1, T1, Lend[cc][(p * 4 + 1) * 16 + j]);
      T2 = fmaf(e2, T2, Lend[cc][(p * 4 + 2) * 16 + j]);
      T3 = fmaf(e3, T3, Lend[cc][(p * 4 + 3) * 16 + j]);
    }
  }
  __syncthreads();

  float u0 = u[h * 16 + p * 4 + 0], u1 = u[h * 16 + p * 4 + 1];
  float u2 = u[h * 16 + p * 4 + 2], u3 = u[h * 16 + p * 4 + 3];
  S0 = Sini[c][(p * 4 + 0) * 16 + j];
  S1 = Sini[c][(p * 4 + 1) * 16 + j];
  S2 = Sini[c][(p * 4 + 2) * 16 + j];
  S3 = Sini[c][(p * 4 + 3) * 16 + j];
  for (int t0 = 0; t0 < 128; t0 += 16) {
    size_t off = base + (size_t)t0 * 16;
    ushort4 rv = ((const ushort4*)(r + off))[lane];
    ushort4 kv4 = ((const ushort4*)(k + off))[lane];
    ushort4 vv = ((const ushort4*)(v + off))[lane];
    float4 wv = ((const float4*)(wd + off))[lane];
    ((float4*)lr[c])[lane] = make_float4(b2f(rv.x), b2f(rv.y), b2f(rv.z), b2f(rv.w));
    ((float4*)lk[c])[lane] = make_float4(b2f(kv4.x), b2f(kv4.y), b2f(kv4.z), b2f(kv4.w));
    ((float4*)lv[c])[lane] = make_float4(b2f(vv.x), b2f(vv.y), b2f(vv.z), b2f(vv.w));
    ((float4*)lw[c])[lane] = wv;
#pragma unroll
    for (int s = 0; s < 16; s++) {
      float4 rr = *(const float4*)(lr[c] + s * 16 + p * 4);
      float4 kk = *(const float4*)(lk[c] + s * 16 + p * 4);
      float4 ww = *(const float4*)(lw[c] + s * 16 + p * 4);
      float vj = lv[c][s * 16 + j];
      float kv, part;
      kv = kk.x * vj; part = rr.x * fmaf(u0, kv, S0); S0 = fmaf(ww.x, S0, kv);
      kv = kk.y * vj; part = fmaf(rr.y, fmaf(u1, kv, S1), part); S1 = fmaf(ww.y, S1, kv);
      kv = kk.z * vj; part = fmaf(rr.z, fmaf(u2, kv, S2), part); S2 = fmaf(ww.z, S2, kv);
      kv = kk.w * vj; part = fmaf(rr.w, fmaf(u3, kv, S3), part); S3 = fmaf(ww.w, S3, kv);
      part += __shfl_xor(part, 16, 64);
      part += __shfl_xor(part, 32, 64);
      if (p == 0) y[(size_t)(b * TT + c * 128 + t0 + s) * CC + h * 16 + j] = part;
    }
  }
}

// ---------------- LayerNorm -> bf16 ----------------
__global__ __launch_bounds__(256) void ln_fused(const float* __restrict__ y,
                                                const float* __restrict__ g,
                                                const float* __restrict__ be,
                                                unsigned short* __restrict__ out) {
  int row = blockIdx.x;
  int tid = threadIdx.x;
  float4 val = ((const float4*)(y + (size_t)row * CC))[tid];
  float s = val.x + val.y + val.z + val.w;
  float sq = val.x * val.x + val.y * val.y + val.z * val.z + val.w * val.w;
#pragma unroll
  for (int m = 1; m < 64; m <<= 1) {
    s += __shfl_xor(s, m, 64);
    sq += __shfl_xor(sq, m, 64);
  }
  __shared__ float ss[4], s2[4];
  int w = tid >> 6;
  if ((tid & 63) == 0) { ss[w] = s; s2[w] = sq; }
  __syncthreads();
  s = ss[0] + ss[1] + ss[2] + ss[3];
  sq = s2[0] + s2[1] + s2[2] + s2[3];
  float mu = s * (1.f / 1024.f);
  float var = sq * (1.f / 1024.f) - mu * mu;
  float rstd = rsqrtf(var + 1e-5f);
  float4 gg = ((const float4*)g)[tid];
  float4 bb = ((const float4*)be)[tid];
  ushort4 o;
  o.x = f2b((val.x - mu) * rstd * gg.x + bb.x);
  o.y = f2b((val.y - mu) * rstd * gg.y + bb.y);
  o.z = f2b((val.z - mu) * rstd * gg.z + bb.z);
  o.w = f2b((val.w - mu) * rstd * gg.w + bb.w);
  ((ushort4*)(out + (size_t)row * CC))[tid] = o;
}

extern "C" void kernel_launch(void* const* d_in, const int* in_sizes, int n_in,
                              void* d_out, int out_size, void* d_ws, size_t ws_size,
                              hipStream_t stream) {
  (void)in_sizes; (void)n_in; (void)out_size; (void)ws_size;
  const float* x = (const float*)d_in[0];
  const float* tmx = (const float*)d_in[1];
  const float* tmw = (const float*)d_in[2];
  const float* tmk = (const float*)d_in[3];
  const float* tmv = (const float*)d_in[4];
  const float* tmr = (const float*)d_in[5];
  const float* w1 = (const float*)d_in[6];
  const float* w2 = (const float*)d_in[7];
  const float* tdecay = (const float*)d_in[8];
  const float* dw1 = (const float*)d_in[9];
  const float* dw2 = (const float*)d_in[10];
  const float* faaaa = (const float*)d_in[11];
  const float* Wr = (const float*)d_in[12];
  const float* Wk = (const float*)d_in[13];
  const float* Wv = (const float*)d_in[14];
  const float* Wo = (const float*)d_in[15];
  const float* lng = (const float*)d_in[16];
  const float* lnb = (const float*)d_in[17];
  float* out = (float*)d_out;

  char* ws = (char*)d_ws;
  const size_t MBy = 1ull << 20;
  unsigned short* rb   = (unsigned short*)(ws + 0);        // 16MB bf16 [BH,T,16]
  unsigned short* kbuf = (unsigned short*)(ws + 16 * MBy); // 16MB
  unsigned short* vbuf = (unsigned short*)(ws + 32 * MBy); // 16MB
  float* wdb = (float*)(ws + 48 * MBy);                    // 32MB f32 [BH,T,16]
  unsigned short* xb    = (unsigned short*)(ws + 80 * MBy);  // 16MB (dead after gates)
  unsigned short* xxb16 = (unsigned short*)(ws + 96 * MBy);  // 16MB (dead after gates)
  float* yb = (float*)(ws + 80 * MBy);                       // 32MB, aliases xb+xxb16
  unsigned short* xxxb = (unsigned short*)(ws + 112 * MBy);  // 16MB (dead after mixer)
  unsigned short* xwb  = (unsigned short*)(ws + 112 * MBy);  // aliases xxx
  unsigned short* xrb  = (unsigned short*)(ws + 128 * MBy);  // 16MB
  unsigned short* xkb  = (unsigned short*)(ws + 144 * MBy);  // 16MB (dead after proj)
  unsigned short* ynb  = (unsigned short*)(ws + 144 * MBy);  // aliases xkb
  unsigned short* xvb  = (unsigned short*)(ws + 160 * MBy);  // 16MB
  // split-K partial scratch, placed in regions dead at their use time:
  float* mixP  = (float*)(ws + 128 * MBy);  // 16MB f32 [4][8192][128]; xrb written later
  float* decP  = (float*)(ws + 0);          // 8MB  f32 [4][8192][64];  rb written later
  unsigned short* mtmpb = (unsigned short*)(ws + 176 * MBy); // 2MB bf16 [8192,128]
  unsigned short* dtmpb = (unsigned short*)(ws + 178 * MBy); // 1MB bf16 [8192,64]
  char* wreg = ws + 179 * MBy;
  unsigned short* w1t  = (unsigned short*)(wreg);               // [128,1024]
  unsigned short* w2t  = (unsigned short*)(wreg + 256 * 1024);  // 4x[1024,32]
  unsigned short* dw1t = (unsigned short*)(wreg + 512 * 1024);  // [64,1024] (+pad reads ok)
  unsigned short* dw2t = (unsigned short*)(wreg + 768 * 1024);  // [1024,64]
  unsigned short* Wrt  = (unsigned short*)(wreg + 1024 * 1024); // [1024,1024]
  unsigned short* Wkt = Wrt + 1024 * 1024;
  unsigned short* Wvt = Wkt + 1024 * 1024;
  unsigned short* Wot = Wvt + 1024 * 1024;

  dim3 tb(32, 8);
  {
    TransAll ta;
    int st = 0, si = 0;
    auto add = [&](const float* in, unsigned short* o, int R, int C) {
      int tx = (C + 31) / 32, ty = (R + 31) / 32;
      ta.seg[si++] = TSeg{in, o, R, C, tx, st};
      st += tx * ty;
    };
    add(Wr, Wrt, 1024, 1024);
    add(Wk, Wkt, 1024, 1024);
    add(Wv, Wvt, 1024, 1024);
    add(Wo, Wot, 1024, 1024);
    for (int g = 0; g < 4; g++)
      add(w2 + (size_t)g * 32 * 1024, w2t + (size_t)g * 1024 * 32, 32, 1024);
    add(w1, w1t, 1024, 128);
    add(dw1, dw1t, 1024, 64);
    add(dw2, dw2t, 64, 1024);
    ta.nseg = si;
    transpose_all<<<st, tb, 0, stream>>>(ta);
  }

  shift_mix<<<8192, 256, 0, stream>>>(x, tmx, xb, xxb16, xxxb);

  // mixer: mtmp = tanh(xxx @ w1) via split-K(4)
  gemm_splitk<<<dim3(4, 64), 256, 0, stream>>>(xxxb, w1t, 128, 256, 1024, 1024, 128, mixP);
  reduce_tanh<<<1024, 256, 0, stream>>>(mixP, mtmpb, 8192 * 128 / 4, 4, 8192 * 128);

  // gates (batched): xg = bf16(x + xx*(tm_g + mtmp[:,g] @ w2[g]))
  {
    GateArgs ga;
    ga.A = mtmpb; ga.Bt = w2t;
    ga.out[0] = xwb; ga.out[1] = xkb; ga.out[2] = xvb; ga.out[3] = xrb;
    ga.tm[0] = tmw; ga.tm[1] = tmk; ga.tm[2] = tmv; ga.tm[3] = tmr;
    ga.xb = xb; ga.xxb = xxb16;
    gemm_gate4<<<dim3(8, 64, 4), 256, 0, stream>>>(ga);
  }
  // decay: dtmp = tanh(xw @ dw1) via split-K(4); wd = exp(-exp(tdecay + dtmp @ dw2))
  gemm_splitk<<<dim3(4, 64), 256, 0, stream>>>(xwb, dw1t, 64, 256, 1024, 1024, 64, decP);
  reduce_tanh<<<512, 256, 0, stream>>>(decP, dtmpb, 8192 * 64 / 4, 4, 8192 * 64);
  gemm_bf16<<<dim3(8, 64), 256, 0, stream>>>(dtmpb, dw2t, 1024, 64, 64, 64, 4, 1024,
                                             wdb, nullptr, tdecay);
  // projections (batched, permuted bf16 [BH,T,16])
  {
    ProjArgs pa;
    pa.A[0] = xrb; pa.A[1] = xkb; pa.A[2] = xvb;
    pa.Bt[0] = Wrt; pa.Bt[1] = Wkt; pa.Bt[2] = Wvt;
    pa.out[0] = rb; pa.out[1] = kbuf; pa.out[2] = vbuf;
    gemm_proj3<<<dim3(8, 64, 3), 256, 0, stream>>>(pa);
  }

  wkv_scan2<<<256, 1024, 0, stream>>>(rb, kbuf, vbuf, wdb, faaaa, yb);
  ln_fused<<<8192, 256, 0, stream>>>(yb, lng, lnb, ynb);
  // out = ynorm @ W_o
  gemm_bf16<<<dim3(8, 64), 256, 0, stream>>>(ynb, Wot, 1024, 1024, 1024, 1024, 0, 1024,
                                             out, nullptr, nullptr);
}

// Round 7
// 394.139 us; speedup vs baseline: 2.2579x; 1.1214x over previous
//
#include <hip/hip_runtime.h>
#include <stdint.h>

#define TT 2048
#define CC 1024

typedef short bf16x8 __attribute__((ext_vector_type(8)));
typedef float f32x4 __attribute__((ext_vector_type(4)));
typedef __attribute__((address_space(3))) uint32_t lds_u32_t;
typedef const __attribute__((address_space(1))) uint32_t glb_u32_t;

__device__ inline unsigned short f2b(float f) {
  union { float f; unsigned u; } c; c.f = f;
  unsigned u = c.u;
  return (unsigned short)((u + 0x7fffu + ((u >> 16) & 1u)) >> 16);
}
__device__ inline float b2f(unsigned short s) {
  union { unsigned u; float f; } c; c.u = ((unsigned)s) << 16; return c.f;
}

__device__ inline void gl_lds16(const void* g, void* l) {
  glb_u32_t* gp = (glb_u32_t*)(uintptr_t)g;
  lds_u32_t* lp = (lds_u32_t*)(uint32_t)(uintptr_t)l;
  __builtin_amdgcn_global_load_lds(gp, lp, 16, 0, 0);
}

// XCD-aware swizzle (verified R3: FETCH 200->57MB on proj3). gridDim.y % 8 == 0.
__device__ inline void swiz(int& bx, int& by, int& bz) {
  int nx = gridDim.x, ny = gridDim.y;
  int flat = (blockIdx.z * ny + blockIdx.y) * nx + blockIdx.x;
  int xcd = flat & 7;
  int idx = flat >> 3;
  int perz = (nx * ny) >> 3;
  bz = idx / perz;
  int rem = idx - bz * perz;
  int r = rem / nx;
  bx = rem - r * nx;
  by = xcd * (ny >> 3) + r;
}

// ---------------- fused transposes: out[C,R] = bf16(in[R,C]), 11 segments ----------------
struct TSeg { const float* in; unsigned short* out; int R, C, tx, start; };
struct TransAll { TSeg seg[11]; int nseg; };
__global__ void transpose_all(TransAll ta) {
  __shared__ float tile[32][33];
  int bid = blockIdx.x;
  int si = 0;
  while (si + 1 < ta.nseg && bid >= ta.seg[si + 1].start) si++;
  TSeg sg = ta.seg[si];
  int lt = bid - sg.start;
  int bx = lt % sg.tx, by = lt / sg.tx;
  int c0 = bx * 32, r0 = by * 32;
  int tx = threadIdx.x, ty = threadIdx.y;  // 32x8
  for (int i = ty; i < 32; i += 8) {
    int r = r0 + i, c = c0 + tx;
    tile[i][tx] = (r < sg.R && c < sg.C) ? sg.in[(size_t)r * sg.C + c] : 0.f;
  }
  __syncthreads();
  int rr = r0 + tx;
  for (int i = ty; i < 32; i += 8) {
    int cc = c0 + i;
    if (cc < sg.C && rr < sg.R) sg.out[(size_t)cc * sg.R + rr] = f2b(tile[tx][i]);
  }
}

// ---- token shift: xb=bf16(x); xxb=bf16(shift(x)-x); xxx=bf16(x + xx*tmx) ----
__global__ void shift_mix(const float* __restrict__ x, const float* __restrict__ tmx,
                          unsigned short* __restrict__ xb, unsigned short* __restrict__ xxb,
                          unsigned short* __restrict__ xxx) {
  int idx = blockIdx.x * 256 + threadIdx.x;  // float4 groups, 2M total
  int c4 = idx & 255;
  int row = idx >> 8;
  int t = row & (TT - 1);
  const float4* x4 = (const float4*)x;
  float4 xv = x4[idx];
  float4 pv = make_float4(0.f, 0.f, 0.f, 0.f);
  if (t > 0) pv = x4[idx - 256];
  float4 d;
  d.x = pv.x - xv.x; d.y = pv.y - xv.y; d.z = pv.z - xv.z; d.w = pv.w - xv.w;
  ushort4 ob;
  ob.x = f2b(xv.x); ob.y = f2b(xv.y); ob.z = f2b(xv.z); ob.w = f2b(xv.w);
  ((ushort4*)xb)[idx] = ob;
  ushort4 od;
  od.x = f2b(d.x); od.y = f2b(d.y); od.z = f2b(d.z); od.w = f2b(d.w);
  ((ushort4*)xxb)[idx] = od;
  float4 tm = ((const float4*)tmx)[c4];
  ushort4 o;
  o.x = f2b(xv.x + d.x * tm.x);
  o.y = f2b(xv.y + d.y * tm.y);
  o.z = f2b(xv.z + d.z * tm.z);
  o.w = f2b(xv.w + d.w * tm.w);
  ((ushort4*)xxx)[idx] = o;
}

// ---------------- pipelined MFMA core: 128x128 tile, BK=32, 3 LDS stages ----------------
// COALESCED staging (R6): one gl_lds16 covers 16 rows x 64B (lane = row*4+chunk),
// so every 64B line is fully consumed by one instruction (16 full-line requests
// per instr vs 64 quarter-used in R3-R5 -> 4x fewer L2 requests; the scattered-
// request rate was the 111us/18%-MfmaUtil limiter). LDS slot-chunk is
// XOR-swizzled (chunk ^ ((row>>1)&3)) so ds_read_b128 stays ~2-way banked (free)
// without padding, preserving gl_lds16's contiguous-destination rule.
__device__ __forceinline__ void gemm_core_pipe(
    const unsigned short* __restrict__ A, const unsigned short* __restrict__ Bt,
    int k0beg, int k0end, int lda, int ldb, int rowBase, int colBase,
    unsigned short* As, unsigned short* Bs, f32x4 acc[4][4], int w, int lane,
    int quad, int l16, int waveM, int waveN) {
#pragma unroll
  for (int i = 0; i < 4; i++)
#pragma unroll
    for (int j = 0; j < 4; j++) acc[i][j] = (f32x4){0.f, 0.f, 0.f, 0.f};
  const int SSB = 8192;  // bytes per stage (128 rows x 64 B)
  const int nIter = (k0end - k0beg) >> 5;
  // staging lane mapping: row_local = lane>>2 within a 16-row group,
  // global chunk = (lane&3) ^ ((lane>>3)&3)  (XOR swizzle, per-lane constant)
  int rl = lane >> 2;
  int cl = (lane & 3) ^ ((lane >> 3) & 3);
  int rA0 = w * 16 + rl, rA1 = (w + 4) * 16 + rl;
  const unsigned short* gA0 = A + (size_t)(rowBase + rA0) * lda + cl * 8 + k0beg;
  const unsigned short* gA1 = A + (size_t)(rowBase + rA1) * lda + cl * 8 + k0beg;
  const unsigned short* gB0 = Bt + (size_t)(colBase + rA0) * ldb + cl * 8 + k0beg;
  const unsigned short* gB1 = Bt + (size_t)(colBase + rA1) * ldb + cl * 8 + k0beg;
  char* dA0 = (char*)As + w * 1024;
  char* dA1 = (char*)As + (w + 4) * 1024;
  char* dB0 = (char*)Bs + w * 1024;
  char* dB1 = (char*)Bs + (w + 4) * 1024;
  // MFMA-side read offsets: m*64B + (quad ^ ((l16>>1)&3))*16B  (mt adds 1024B)
  int sw = quad ^ ((l16 >> 1) & 3);
  int aoff = (waveM + l16) * 64 + sw * 16;
  int boff = (waveN + l16) * 64 + sw * 16;

#define ISSUE(it, st)                               \
  {                                                 \
    int ko = (it) * 32;                             \
    gl_lds16(gA0 + ko, dA0 + (st) * SSB);           \
    gl_lds16(gA1 + ko, dA1 + (st) * SSB);           \
    gl_lds16(gB0 + ko, dB0 + (st) * SSB);           \
    gl_lds16(gB1 + ko, dB1 + (st) * SSB);           \
  }

  ISSUE(0, 0)
  if (nIter > 1) ISSUE(1, 1)
  int stage = 0;
  for (int it = 0; it < nIter; ++it) {
    if (it + 1 < nIter) {
      asm volatile("s_waitcnt vmcnt(4)\ns_barrier" ::: "memory");
    } else {
      asm volatile("s_waitcnt vmcnt(0)\ns_barrier" ::: "memory");
    }
    if (it + 2 < nIter) {
      int ns = stage + 2; if (ns >= 3) ns -= 3;
      ISSUE(it + 2, ns)
    }
    const char* Ab = (const char*)As + stage * SSB;
    const char* Bb = (const char*)Bs + stage * SSB;
    bf16x8 af[4], bfr[4];
#pragma unroll
    for (int mt = 0; mt < 4; mt++)
      af[mt] = *(const bf16x8*)(Ab + aoff + mt * 1024);
#pragma unroll
    for (int nt = 0; nt < 4; nt++)
      bfr[nt] = *(const bf16x8*)(Bb + boff + nt * 1024);
#pragma unroll
    for (int mt = 0; mt < 4; mt++)
#pragma unroll
      for (int nt = 0; nt < 4; nt++)
        acc[mt][nt] = __builtin_amdgcn_mfma_f32_16x16x32_bf16(af[mt], bfr[nt], acc[mt][nt], 0, 0, 0);
    stage = stage + 1; if (stage >= 3) stage -= 3;
  }
#undef ISSUE
}

// ---------------- generic GEMM (pipelined): modes 0 f32, 4 decay perm ----------------
__global__ __launch_bounds__(256) void gemm_bf16(
    const unsigned short* __restrict__ A, const unsigned short* __restrict__ Bt,
    int N, int K, int lda, int ldb, int mode, int ldc,
    float* __restrict__ outF, unsigned short* __restrict__ outB,
    const float* __restrict__ tm) {
  __shared__ __align__(16) unsigned short As[3 * 4096];
  __shared__ __align__(16) unsigned short Bs[3 * 4096];
  int bx, by, bz;
  swiz(bx, by, bz);
  (void)bz;
  int tid = threadIdx.x;
  int w = tid >> 6, lane = tid & 63;
  int quad = lane >> 4, l16 = lane & 15;
  int rowBase = by * 128;
  int colBase = bx * 128;
  int waveM = (w >> 1) * 64, waveN = (w & 1) * 64;
  f32x4 acc[4][4];
  gemm_core_pipe(A, Bt, 0, K, lda, ldb, rowBase, colBase, As, Bs, acc, w, lane, quad, l16, waveM, waveN);
#pragma unroll
  for (int mt = 0; mt < 4; mt++)
#pragma unroll
    for (int nt = 0; nt < 4; nt++)
#pragma unroll
      for (int rg = 0; rg < 4; rg++) {
        int row = rowBase + waveM + mt * 16 + quad * 4 + rg;
        int col = colBase + waveN + nt * 16 + l16;
        if (col >= N) continue;
        float val = acc[mt][nt][rg];
        if (mode == 0) {
          outF[(size_t)row * ldc + col] = val;
        } else {
          int b = row >> 11, t = row & (TT - 1), h = col >> 4, n = col & 15;
          outF[(size_t)((b * 64 + h) * TT + t) * 16 + n] = expf(-expf(tm[col] + val));
        }
      }
}

// ---------------- split-K GEMM (pipelined): partials f32 [S][M][ldp] ----------------
__global__ __launch_bounds__(256) void gemm_splitk(
    const unsigned short* __restrict__ A, const unsigned short* __restrict__ Bt,
    int N, int Kc, int lda, int ldb, int ldp, float* __restrict__ part) {
  __shared__ __align__(16) unsigned short As[3 * 4096];
  __shared__ __align__(16) unsigned short Bs[3 * 4096];
  int s = blockIdx.x, by = blockIdx.y;
  int M = gridDim.y * 128;
  int tid = threadIdx.x;
  int w = tid >> 6, lane = tid & 63;
  int quad = lane >> 4, l16 = lane & 15;
  int rowBase = by * 128;
  int waveM = (w >> 1) * 64, waveN = (w & 1) * 64;
  f32x4 acc[4][4];
  gemm_core_pipe(A, Bt, s * Kc, (s + 1) * Kc, lda, ldb, rowBase, 0, As, Bs, acc, w, lane, quad, l16, waveM, waveN);
  float* pb = part + (size_t)s * M * ldp;
#pragma unroll
  for (int mt = 0; mt < 4; mt++)
#pragma unroll
    for (int nt = 0; nt < 4; nt++)
#pragma unroll
      for (int rg = 0; rg < 4; rg++) {
        int row = rowBase + waveM + mt * 16 + quad * 4 + rg;
        int col = waveN + nt * 16 + l16;
        if (col < N) pb[(size_t)row * ldp + col] = acc[mt][nt][rg];
      }
}

// ---------------- reduce split-K partials + tanh -> bf16 ----------------
__global__ __launch_bounds__(256) void reduce_tanh(
    const float* __restrict__ part, unsigned short* __restrict__ out,
    int total4, int S, int strideElems) {
  int idx = blockIdx.x * 256 + threadIdx.x;
  if (idx >= total4) return;
  float4 a = ((const float4*)part)[idx];
  for (int s = 1; s < S; s++) {
    float4 b = ((const float4*)(part + (size_t)s * strideElems))[idx];
    a.x += b.x; a.y += b.y; a.z += b.z; a.w += b.w;
  }
  ushort4 o;
  o.x = f2b(tanhf(a.x)); o.y = f2b(tanhf(a.y));
  o.z = f2b(tanhf(a.z)); o.w = f2b(tanhf(a.w));
  ((ushort4*)out)[idx] = o;
}

// ---------------- batched gate GEMM (K=32): epilogue x + xx*(tm+acc) ----------------
struct GateArgs {
  const unsigned short* A;
  const unsigned short* Bt;
  unsigned short* out[4];
  const float* tm[4];
  const unsigned short* xb;
  const unsigned short* xxb;
};
__global__ __launch_bounds__(256) void gemm_gate4(GateArgs ga) {
  __shared__ __align__(16) unsigned short As[3 * 4096];
  __shared__ __align__(16) unsigned short Bs[3 * 4096];
  // 4 gates of the same (row,col) tile consecutive on one XCD (xb/xxb L2 reuse)
  int flat = (blockIdx.z * 64 + blockIdx.y) * 8 + blockIdx.x;
  int xcd = flat & 7;
  int idx = flat >> 3;
  int z = idx & 3;
  int tile = idx >> 2;
  int by = xcd * 8 + (tile >> 3);
  int bx = tile & 7;
  const unsigned short* A = ga.A + z * 32;
  const unsigned short* Bt = ga.Bt + (size_t)z * 1024 * 32;
  unsigned short* outB = ga.out[z];
  const float* tm = ga.tm[z];
  int tid = threadIdx.x;
  int w = tid >> 6, lane = tid & 63;
  int quad = lane >> 4, l16 = lane & 15;
  int rowBase = by * 128;
  int colBase = bx * 128;
  int waveM = (w >> 1) * 64, waveN = (w & 1) * 64;
  f32x4 acc[4][4];
  gemm_core_pipe(A, Bt, 0, 32, 128, 32, rowBase, colBase, As, Bs, acc, w, lane, quad, l16, waveM, waveN);
#pragma unroll
  for (int mt = 0; mt < 4; mt++)
#pragma unroll
    for (int nt = 0; nt < 4; nt++)
#pragma unroll
      for (int rg = 0; rg < 4; rg++) {
        int row = rowBase + waveM + mt * 16 + quad * 4 + rg;
        int col = colBase + waveN + nt * 16 + l16;
        size_t o = (size_t)row * CC + col;
        float xv = b2f(ga.xb[o]), xxv = b2f(ga.xxb[o]);
        outB[o] = f2b(xv + xxv * (tm[col] + acc[mt][nt][rg]));
      }
}

// ---------------- batched projection GEMM (pipelined): perm bf16 store ----------------
struct ProjArgs {
  const unsigned short* A[3];
  const unsigned short* Bt[3];
  unsigned short* out[3];
};
__global__ __launch_bounds__(256) void gemm_proj3(ProjArgs pa) {
  __shared__ __align__(16) unsigned short As[3 * 4096];
  __shared__ __align__(16) unsigned short Bs[3 * 4096];
  int bx, by, bz;
  swiz(bx, by, bz);
  const unsigned short* A = pa.A[bz];
  const unsigned short* Bt = pa.Bt[bz];
  unsigned short* outB = pa.out[bz];
  int tid = threadIdx.x;
  int w = tid >> 6, lane = tid & 63;
  int quad = lane >> 4, l16 = lane & 15;
  int rowBase = by * 128;
  int colBase = bx * 128;
  int waveM = (w >> 1) * 64, waveN = (w & 1) * 64;
  f32x4 acc[4][4];
  gemm_core_pipe(A, Bt, 0, 1024, 1024, 1024, rowBase, colBase, As, Bs, acc, w, lane, quad, l16, waveM, waveN);
#pragma unroll
  for (int mt = 0; mt < 4; mt++)
#pragma unroll
    for (int nt = 0; nt < 4; nt++)
#pragma unroll
      for (int rg = 0; rg < 4; rg++) {
        int row = rowBase + waveM + mt * 16 + quad * 4 + rg;
        int col = colBase + waveN + nt * 16 + l16;
        int b = row >> 11, t = row & (TT - 1), h = col >> 4, n = col & 15;
        outB[(size_t)((b * 64 + h) * TT + t) * 16 + n] = f2b(acc[mt][nt][rg]);
      }
}

// ---------------- WKV6 chunk-parallel scan (16 waves per (b,h)) ----------------
__global__ __launch_bounds__(1024) void wkv_scan2(
    const unsigned short* __restrict__ r, const unsigned short* __restrict__ k,
    const unsigned short* __restrict__ v, const float* __restrict__ wd,
    const float* __restrict__ u, float* __restrict__ y) {
  __shared__ __align__(16) float lr[16][256];
  __shared__ __align__(16) float lk[16][256];
  __shared__ __align__(16) float lv[16][256];
  __shared__ __align__(16) float lw[16][256];
  __shared__ __align__(16) float Lend[16][256];
  __shared__ __align__(16) float Sini[16][256];
  __shared__ float Eend[16][16];
  int bh = blockIdx.x;
  int b = bh >> 6, h = bh & 63;
  int tid = threadIdx.x;
  int c = tid >> 6, lane = tid & 63;
  int j = lane & 15, p = lane >> 4;
  size_t base = (size_t)bh * TT * 16 + (size_t)c * 128 * 16;

  float S0 = 0.f, S1 = 0.f, S2 = 0.f, S3 = 0.f;
  float E0 = 1.f, E1 = 1.f, E2 = 1.f, E3 = 1.f;
  for (int t0 = 0; t0 < 128; t0 += 16) {
    size_t off = base + (size_t)t0 * 16;
    ushort4 kv4 = ((const ushort4*)(k + off))[lane];
    ushort4 vv = ((const ushort4*)(v + off))[lane];
    float4 wv = ((const float4*)(wd + off))[lane];
    ((float4*)lk[c])[lane] = make_float4(b2f(kv4.x), b2f(kv4.y), b2f(kv4.z), b2f(kv4.w));
    ((float4*)lv[c])[lane] = make_float4(b2f(vv.x), b2f(vv.y), b2f(vv.z), b2f(vv.w));
    ((float4*)lw[c])[lane] = wv;
#pragma unroll
    for (int s = 0; s < 16; s++) {
      float4 kk = *(const float4*)(lk[c] + s * 16 + p * 4);
      float4 ww = *(const float4*)(lw[c] + s * 16 + p * 4);
      float vj = lv[c][s * 16 + j];
      S0 = fmaf(ww.x, S0, kk.x * vj); E0 *= ww.x;
      S1 = fmaf(ww.y, S1, kk.y * vj); E1 *= ww.y;
      S2 = fmaf(ww.z, S2, kk.z * vj); E2 *= ww.z;
      S3 = fmaf(ww.w, S3, kk.w * vj); E3 *= ww.w;
    }
  }
  Lend[c][(p * 4 + 0) * 16 + j] = S0;
  Lend[c][(p * 4 + 1) * 16 + j] = S1;
  Lend[c][(p * 4 + 2) * 16 + j] = S2;
  Lend[c][(p * 4 + 3) * 16 + j] = S3;
  if (j == 0) {
    Eend[c][p * 4 + 0] = E0;
    Eend[c][p * 4 + 1] = E1;
    Eend[c][p * 4 + 2] = E2;
    Eend[c][p * 4 + 3] = E3;
  }
  __syncthreads();

  if (c == 0) {
    float T0 = 0.f, T1 = 0.f, T2 = 0.f, T3 = 0.f;
    for (int cc = 0; cc < 16; cc++) {
      Sini[cc][(p * 4 + 0) * 16 + j] = T0;
      Sini[cc][(p * 4 + 1) * 16 + j] = T1;
      Sini[cc][(p * 4 + 2) * 16 + j] = T2;
      Sini[cc][(p * 4 + 3) * 16 + j] = T3;
      float e0 = Eend[cc][p * 4 + 0], e1 = Eend[cc][p * 4 + 1];
      float e2 = Eend[cc][p * 4 + 2], e3 = Eend[cc][p * 4 + 3];
      T0 = fmaf(e0, T0, Lend[cc][(p * 4 + 0) * 16 + j]);
      T1 = fmaf(e1, T1, Lend[cc][(p * 4 + 1) * 16 + j]);
      T2 = fmaf(e2, T2, Lend[cc][(p * 4 + 2) * 16 + j]);
      T3 = fmaf(e3, T3, Lend[cc][(p * 4 + 3) * 16 + j]);
    }
  }
  __syncthreads();

  float u0 = u[h * 16 + p * 4 + 0], u1 = u[h * 16 + p * 4 + 1];
  float u2 = u[h * 16 + p * 4 + 2], u3 = u[h * 16 + p * 4 + 3];
  S0 = Sini[c][(p * 4 + 0) * 16 + j];
  S1 = Sini[c][(p * 4 + 1) * 16 + j];
  S2 = Sini[c][(p * 4 + 2) * 16 + j];
  S3 = Sini[c][(p * 4 + 3) * 16 + j];
  for (int t0 = 0; t0 < 128; t0 += 16) {
    size_t off = base + (size_t)t0 * 16;
    ushort4 rv = ((const ushort4*)(r + off))[lane];
    ushort4 kv4 = ((const ushort4*)(k + off))[lane];
    ushort4 vv = ((const ushort4*)(v + off))[lane];
    float4 wv = ((const float4*)(wd + off))[lane];
    ((float4*)lr[c])[lane] = make_float4(b2f(rv.x), b2f(rv.y), b2f(rv.z), b2f(rv.w));
    ((float4*)lk[c])[lane] = make_float4(b2f(kv4.x), b2f(kv4.y), b2f(kv4.z), b2f(kv4.w));
    ((float4*)lv[c])[lane] = make_float4(b2f(vv.x), b2f(vv.y), b2f(vv.z), b2f(vv.w));
    ((float4*)lw[c])[lane] = wv;
#pragma unroll
    for (int s = 0; s < 16; s++) {
      float4 rr = *(const float4*)(lr[c] + s * 16 + p * 4);
      float4 kk = *(const float4*)(lk[c] + s * 16 + p * 4);
      float4 ww = *(const float4*)(lw[c] + s * 16 + p * 4);
      float vj = lv[c][s * 16 + j];
      float kv, part;
      kv = kk.x * vj; part = rr.x * fmaf(u0, kv, S0); S0 = fmaf(ww.x, S0, kv);
      kv = kk.y * vj; part = fmaf(rr.y, fmaf(u1, kv, S1), part); S1 = fmaf(ww.y, S1, kv);
      kv = kk.z * vj; part = fmaf(rr.z, fmaf(u2, kv, S2), part); S2 = fmaf(ww.z, S2, kv);
      kv = kk.w * vj; part = fmaf(rr.w, fmaf(u3, kv, S3), part); S3 = fmaf(ww.w, S3, kv);
      part += __shfl_xor(part, 16, 64);
      part += __shfl_xor(part, 32, 64);
      if (p == 0) y[(size_t)(b * TT + c * 128 + t0 + s) * CC + h * 16 + j] = part;
    }
  }
}

// ---------------- LayerNorm -> bf16 ----------------
__global__ __launch_bounds__(256) void ln_fused(const float* __restrict__ y,
                                                const float* __restrict__ g,
                                                const float* __restrict__ be,
                                                unsigned short* __restrict__ out) {
  int row = blockIdx.x;
  int tid = threadIdx.x;
  float4 val = ((const float4*)(y + (size_t)row * CC))[tid];
  float s = val.x + val.y + val.z + val.w;
  float sq = val.x * val.x + val.y * val.y + val.z * val.z + val.w * val.w;
#pragma unroll
  for (int m = 1; m < 64; m <<= 1) {
    s += __shfl_xor(s, m, 64);
    sq += __shfl_xor(sq, m, 64);
  }
  __shared__ float ss[4], s2[4];
  int w = tid >> 6;
  if ((tid & 63) == 0) { ss[w] = s; s2[w] = sq; }
  __syncthreads();
  s = ss[0] + ss[1] + ss[2] + ss[3];
  sq = s2[0] + s2[1] + s2[2] + s2[3];
  float mu = s * (1.f / 1024.f);
  float var = sq * (1.f / 1024.f) - mu * mu;
  float rstd = rsqrtf(var + 1e-5f);
  float4 gg = ((const float4*)g)[tid];
  float4 bb = ((const float4*)be)[tid];
  ushort4 o;
  o.x = f2b((val.x - mu) * rstd * gg.x + bb.x);
  o.y = f2b((val.y - mu) * rstd * gg.y + bb.y);
  o.z = f2b((val.z - mu) * rstd * gg.z + bb.z);
  o.w = f2b((val.w - mu) * rstd * gg.w + bb.w);
  ((ushort4*)(out + (size_t)row * CC))[tid] = o;
}

extern "C" void kernel_launch(void* const* d_in, const int* in_sizes, int n_in,
                              void* d_out, int out_size, void* d_ws, size_t ws_size,
                              hipStream_t stream) {
  (void)in_sizes; (void)n_in; (void)out_size; (void)ws_size;
  const float* x = (const float*)d_in[0];
  const float* tmx = (const float*)d_in[1];
  const float* tmw = (const float*)d_in[2];
  const float* tmk = (const float*)d_in[3];
  const float* tmv = (const float*)d_in[4];
  const float* tmr = (const float*)d_in[5];
  const float* w1 = (const float*)d_in[6];
  const float* w2 = (const float*)d_in[7];
  const float* tdecay = (const float*)d_in[8];
  const float* dw1 = (const float*)d_in[9];
  const float* dw2 = (const float*)d_in[10];
  const float* faaaa = (const float*)d_in[11];
  const float* Wr = (const float*)d_in[12];
  const float* Wk = (const float*)d_in[13];
  const float* Wv = (const float*)d_in[14];
  const float* Wo = (const float*)d_in[15];
  const float* lng = (const float*)d_in[16];
  const float* lnb = (const float*)d_in[17];
  float* out = (float*)d_out;

  char* ws = (char*)d_ws;
  const size_t MBy = 1ull << 20;
  unsigned short* rb   = (unsigned short*)(ws + 0);        // 16MB bf16 [BH,T,16]
  unsigned short* kbuf = (unsigned short*)(ws + 16 * MBy); // 16MB
  unsigned short* vbuf = (unsigned short*)(ws + 32 * MBy); // 16MB
  float* wdb = (float*)(ws + 48 * MBy);                    // 32MB f32 [BH,T,16]
  unsigned short* xb    = (unsigned short*)(ws + 80 * MBy);  // 16MB (dead after gates)
  unsigned short* xxb16 = (unsigned short*)(ws + 96 * MBy);  // 16MB (dead after gates)
  float* yb = (float*)(ws + 80 * MBy);                       // 32MB, aliases xb+xxb16
  unsigned short* xxxb = (unsigned short*)(ws + 112 * MBy);  // 16MB (dead after mixer)
  unsigned short* xwb  = (unsigned short*)(ws + 112 * MBy);  // aliases xxx
  unsigned short* xrb  = (unsigned short*)(ws + 128 * MBy);  // 16MB
  unsigned short* xkb  = (unsigned short*)(ws + 144 * MBy);  // 16MB (dead after proj)
  unsigned short* ynb  = (unsigned short*)(ws + 144 * MBy);  // aliases xkb
  unsigned short* xvb  = (unsigned short*)(ws + 160 * MBy);  // 16MB
  // split-K partial scratch, placed in regions dead at their use time:
  float* mixP  = (float*)(ws + 128 * MBy);  // 16MB f32 [4][8192][128]; xrb written later
  float* decP  = (float*)(ws + 0);          // 8MB  f32 [4][8192][64];  rb written later
  unsigned short* mtmpb = (unsigned short*)(ws + 176 * MBy); // 2MB bf16 [8192,128]
  unsigned short* dtmpb = (unsigned short*)(ws + 178 * MBy); // 1MB bf16 [8192,64]
  char* wreg = ws + 179 * MBy;
  unsigned short* w1t  = (unsigned short*)(wreg);               // [128,1024]
  unsigned short* w2t  = (unsigned short*)(wreg + 256 * 1024);  // 4x[1024,32]
  unsigned short* dw1t = (unsigned short*)(wreg + 512 * 1024);  // [64,1024] (+pad reads ok)
  unsigned short* dw2t = (unsigned short*)(wreg + 768 * 1024);  // [1024,64]
  unsigned short* Wrt  = (unsigned short*)(wreg + 1024 * 1024); // [1024,1024]
  unsigned short* Wkt = Wrt + 1024 * 1024;
  unsigned short* Wvt = Wkt + 1024 * 1024;
  unsigned short* Wot = Wvt + 1024 * 1024;

  dim3 tb(32, 8);
  {
    TransAll ta;
    int st = 0, si = 0;
    auto add = [&](const float* in, unsigned short* o, int R, int C) {
      int tx = (C + 31) / 32, ty = (R + 31) / 32;
      ta.seg[si++] = TSeg{in, o, R, C, tx, st};
      st += tx * ty;
    };
    add(Wr, Wrt, 1024, 1024);
    add(Wk, Wkt, 1024, 1024);
    add(Wv, Wvt, 1024, 1024);
    add(Wo, Wot, 1024, 1024);
    for (int g = 0; g < 4; g++)
      add(w2 + (size_t)g * 32 * 1024, w2t + (size_t)g * 1024 * 32, 32, 1024);
    add(w1, w1t, 1024, 128);
    add(dw1, dw1t, 1024, 64);
    add(dw2, dw2t, 64, 1024);
    ta.nseg = si;
    transpose_all<<<st, tb, 0, stream>>>(ta);
  }

  shift_mix<<<8192, 256, 0, stream>>>(x, tmx, xb, xxb16, xxxb);

  // mixer: mtmp = tanh(xxx @ w1) via split-K(4)
  gemm_splitk<<<dim3(4, 64), 256, 0, stream>>>(xxxb, w1t, 128, 256, 1024, 1024, 128, mixP);
  reduce_tanh<<<1024, 256, 0, stream>>>(mixP, mtmpb, 8192 * 128 / 4, 4, 8192 * 128);

  // gates (batched): xg = bf16(x + xx*(tm_g + mtmp[:,g] @ w2[g]))
  {
    GateArgs ga;
    ga.A = mtmpb; ga.Bt = w2t;
    ga.out[0] = xwb; ga.out[1] = xkb; ga.out[2] = xvb; ga.out[3] = xrb;
    ga.tm[0] = tmw; ga.tm[1] = tmk; ga.tm[2] = tmv; ga.tm[3] = tmr;
    ga.xb = xb; ga.xxb = xxb16;
    gemm_gate4<<<dim3(8, 64, 4), 256, 0, stream>>>(ga);
  }
  // decay: dtmp = tanh(xw @ dw1) via split-K(4); wd = exp(-exp(tdecay + dtmp @ dw2))
  gemm_splitk<<<dim3(4, 64), 256, 0, stream>>>(xwb, dw1t, 64, 256, 1024, 1024, 64, decP);
  reduce_tanh<<<512, 256, 0, stream>>>(decP, dtmpb, 8192 * 64 / 4, 4, 8192 * 64);
  gemm_bf16<<<dim3(8, 64), 256, 0, stream>>>(dtmpb, dw2t, 1024, 64, 64, 64, 4, 1024,
                                             wdb, nullptr, tdecay);
  // projections (batched, permuted bf16 [BH,T,16])
  {
    ProjArgs pa;
    pa.A[0] = xrb; pa.A[1] = xkb; pa.A[2] = xvb;
    pa.Bt[0] = Wrt; pa.Bt[1] = Wkt; pa.Bt[2] = Wvt;
    pa.out[0] = rb; pa.out[1] = kbuf; pa.out[2] = vbuf;
    gemm_proj3<<<dim3(8, 64, 3), 256, 0, stream>>>(pa);
  }

  wkv_scan2<<<256, 1024, 0, stream>>>(rb, kbuf, vbuf, wdb, faaaa, yb);
  ln_fused<<<8192, 256, 0, stream>>>(yb, lng, lnb, ynb);
  // out = ynorm @ W_o
  gemm_bf16<<<dim3(8, 64), 256, 0, stream>>>(ynb, Wot, 1024, 1024, 1024, 1024, 0, 1024,
                                             out, nullptr, nullptr);
}